// Round 14
// baseline (199.303 us; speedup 1.0000x reference)
//
#include <hip/hip_runtime.h>
#include <math.h>

#define NFEAT 128
#define HC    256   // HEADS*NHID
#define NCLS  16
#define DT_F  0.01f
#define EPS_F 1e-5f
#define LOG2E 1.44269504f

// fp8 e4m3 (OCP, HW-native on gfx950) helpers
__device__ __forceinline__ unsigned char f2f8(float f) {
  int v = __builtin_amdgcn_cvt_pk_fp8_f32(f, f, 0, false);
  return (unsigned char)(v & 0xff);
}
__device__ __forceinline__ float f82f(unsigned int b) {
  return __builtin_amdgcn_cvt_f32_fp8((int)b, 0);
}
__device__ __forceinline__ float f82f_sel0(unsigned int w) { return __builtin_amdgcn_cvt_f32_fp8((int)w, 0); }
__device__ __forceinline__ float f82f_sel1(unsigned int w) { return __builtin_amdgcn_cvt_f32_fp8((int)w, 1); }
__device__ __forceinline__ float f82f_sel2(unsigned int w) { return __builtin_amdgcn_cvt_f32_fp8((int)w, 2); }
__device__ __forceinline__ float f82f_sel3(unsigned int w) { return __builtin_amdgcn_cvt_f32_fp8((int)w, 3); }
// pack 4 floats -> 4x fp8 in one word
__device__ __forceinline__ unsigned int pk4f8(float a, float b, float c, float d) {
  int lo = __builtin_amdgcn_cvt_pk_fp8_f32(a, b, 0, false);
  return (unsigned int)__builtin_amdgcn_cvt_pk_fp8_f32(c, d, lo, true);
}

// logit in log2 domain (att pre-scaled by LOG2E)
__device__ __forceinline__ float edge_logit(unsigned int w, float4 r4, float4 at4) {
  float vx = f82f_sel0(w) + r4.x, vy = f82f_sel1(w) + r4.y;
  float vz = f82f_sel2(w) + r4.z, vw = f82f_sel3(w) + r4.w;
  vx = fmaxf(vx, 0.2f * vx); vy = fmaxf(vy, 0.2f * vy);
  vz = fmaxf(vz, 0.2f * vz); vw = fmaxf(vw, 0.2f * vw);
  float t = vx * at4.x;
  t = fmaf(vy, at4.y, t); t = fmaf(vz, at4.z, t); t = fmaf(vw, at4.w, t);
  return t;
}

// ---------------- K1: enc (Y=relu(x@enc_w+b), X=Y, ybf8=fp8(Y)) + zero deg
__global__ __launch_bounds__(256) void enc_kernel(
    const float* __restrict__ x, const float* __restrict__ w,
    const float* __restrict__ b, float* __restrict__ Y, float* __restrict__ X,
    unsigned char* __restrict__ Ybf, int* __restrict__ deg, int n) {
  __shared__ float ws[NFEAT * 64];
  const int gtid = blockIdx.x * 256 + threadIdx.x, GSZ = gridDim.x * 256;
  for (int t = gtid; t < n; t += GSZ) deg[t] = 0;
  for (int t = threadIdx.x; t < NFEAT * 64; t += blockDim.x) ws[t] = w[t];
  __syncthreads();
  const int wave = threadIdx.x >> 6, lane = threadIdx.x & 63;
  for (int i = blockIdx.x * 4 + wave; i < n; i += gridDim.x * 4) {
    const float* xr = x + (size_t)i * NFEAT;
    float acc = b[lane];
#pragma unroll 8
    for (int k = 0; k < NFEAT; ++k) acc = fmaf(xr[k], ws[k * 64 + lane], acc);
    acc = fmaxf(acc, 0.f);
    const size_t idx = (size_t)i * 64 + lane;
    Y[idx] = acc; X[idx] = acc; Ybf[idx] = f2f8(acc);
  }
}

// ---------------- K2: dual projection (xlb fp8, xr fp32) + deg count + Wext/bb
__global__ __launch_bounds__(256) void proj_kernel(
    const float* __restrict__ Y,
    const float* __restrict__ wl, const float* __restrict__ bl,
    const float* __restrict__ wr, const float* __restrict__ br,
    const int* __restrict__ col, const float* __restrict__ lin_w,
    const float* __restrict__ lin_b, const float* __restrict__ lo_w,
    unsigned char* __restrict__ xlb, float* __restrict__ xr,
    float* __restrict__ Wext, float* __restrict__ bb, int* __restrict__ deg,
    int n, int E) {
  const int half = gridDim.x >> 1;
  const bool doR = (int)blockIdx.x < half;
  const int bid = doR ? blockIdx.x : blockIdx.x - half;
  const float* __restrict__ W = doR ? wr : wl;
  const float* __restrict__ B = doR ? br : bl;
  float wreg[64];
  const int t = threadIdx.x;
#pragma unroll
  for (int k = 0; k < 64; ++k) wreg[k] = W[k * HC + t];
  const float bias = B[t];
  for (int i0 = bid * 4; i0 < n; i0 += half * 4) {
    const float* ap = Y + (size_t)i0 * 64;
    float a0 = bias, a1 = bias, a2 = bias, a3 = bias;
#pragma unroll
    for (int k = 0; k < 64; ++k) {
      const float w = wreg[k];
      a0 = fmaf(ap[k], w, a0);
      a1 = fmaf(ap[64 + k], w, a1);
      a2 = fmaf(ap[128 + k], w, a2);
      a3 = fmaf(ap[192 + k], w, a3);
    }
    if (doR) {
      if (i0 + 0 < n) xr[(size_t)(i0 + 0) * HC + t] = a0;
      if (i0 + 1 < n) xr[(size_t)(i0 + 1) * HC + t] = a1;
      if (i0 + 2 < n) xr[(size_t)(i0 + 2) * HC + t] = a2;
      if (i0 + 3 < n) xr[(size_t)(i0 + 3) * HC + t] = a3;
    } else {
      if (i0 + 0 < n) xlb[(size_t)(i0 + 0) * HC + t] = f2f8(a0);
      if (i0 + 1 < n) xlb[(size_t)(i0 + 1) * HC + t] = f2f8(a1);
      if (i0 + 2 < n) xlb[(size_t)(i0 + 2) * HC + t] = f2f8(a2);
      if (i0 + 3 < n) xlb[(size_t)(i0 + 3) * HC + t] = f2f8(a3);
    }
  }
  // appended independent work: deg count + Wext/bb
  const int gtid = blockIdx.x * 256 + t, GSZ = gridDim.x * 256;
  for (int e = gtid; e < E; e += GSZ) atomicAdd(&deg[col[e]], 1);
  for (int f = gtid; f < 260 * 64; f += GSZ) {
    const int b2 = f >> 6, j = f & 63;
    float a = 0.f;
    if (b2 < 256) {
      const int k = b2 >> 2, h = b2 & 3;
#pragma unroll 8
      for (int c = 0; c < 64; ++c)
        a = fmaf(lin_w[k * HC + h * 64 + c], lo_w[(size_t)(h * 64 + c) * 64 + j], a);
      Wext[b2 * 64 + j] = a;
    } else {
      const int h = b2 - 256;
#pragma unroll 8
      for (int c = 0; c < 64; ++c)
        a = fmaf(lin_b[h * 64 + c], lo_w[(size_t)(h * 64 + c) * 64 + j], a);
      bb[h * 64 + j] = a;
    }
  }
}

// ---------------- K3: single-block exclusive scan (1024 threads) -> offs/cur/dis
__global__ __launch_bounds__(1024) void scan_kernel(
    const int* __restrict__ deg, int* __restrict__ offsets, int* __restrict__ cursor,
    float* __restrict__ dis, int n) {
  __shared__ int part[1024];
  const int t = threadIdx.x;
  const int chunk = (n + 1023) / 1024;
  const int start = t * chunk;
  const int end = min(start + chunk, n);
  int s = 0;
  for (int i = start; i < end; ++i) s += deg[i];
  part[t] = s;
  __syncthreads();
  for (int off = 1; off < 1024; off <<= 1) {
    int v = (t >= off) ? part[t - off] : 0;
    __syncthreads();
    part[t] += v;
    __syncthreads();
  }
  int run = (t == 0) ? 0 : part[t - 1];
  for (int i = start; i < end; ++i) {
    offsets[i] = run;
    cursor[i] = run;
    const int d = deg[i];
    dis[i] = (d > 0) ? rsqrtf((float)d) : 0.f;
    run += d;
  }
}

// ---------------- K4: counting-sort src into CSR order
__global__ __launch_bounds__(256) void scatter_kernel(
    const int* __restrict__ row, const int* __restrict__ col,
    int* __restrict__ cursor, int* __restrict__ srow, int E) {
  int e = blockIdx.x * blockDim.x + threadIdx.x;
  if (e >= E) return;
  int pos = atomicAdd(&cursor[col[e]], 1);
  srow[pos] = row[e];
}

// ---------------- K5: score fused with layer-1. Masked unroll-4 with srow AND
// xlb-word prefetch (one block ahead). Lanes 0-3 write packed edge records in
// parallel (one 32B burst per block).
__global__ __launch_bounds__(256, 8) void score_layer1(
    const int* __restrict__ offs, const int* __restrict__ deg,
    const int* __restrict__ srow,
    const unsigned char* __restrict__ xlb, const float* __restrict__ xr,
    const float* __restrict__ att, const float* __restrict__ dis,
    const float* __restrict__ bb, const float* __restrict__ lo_b,
    const float* __restrict__ Wext, const unsigned char* __restrict__ ybf_in,
    const float* __restrict__ Yin, float* __restrict__ Yout,
    unsigned char* __restrict__ ybf_out, float* __restrict__ X,
    int2* __restrict__ erec, float4* __restrict__ invq, float* __restrict__ fb,
    int n, float c_decay, float c_x, float c_k) {
  const int tid = threadIdx.x, wave = tid >> 6, lane = tid & 63;
  __shared__ float aggl[4][HC];
  __shared__ float partl[4][4][64];
  float4 at4 = ((const float4*)att)[lane];
  at4.x *= LOG2E; at4.y *= LOG2E; at4.z *= LOG2E; at4.w *= LOG2E;
  const unsigned int* xlb4 = (const unsigned int*)xlb;  // 4 fp8 per word
  const float4* xr4 = (const float4*)xr;
  const int i = blockIdx.x * 4 + wave;
  float g0 = 0.f, g1 = 0.f, g2 = 0.f, g3 = 0.f;
  float fbv = 0.f;
  if (i < n) {
    const int s = offs[i], e = s + deg[i];
    if (s >= e) {
      if (lane == 0) invq[i] = make_float4(0.f, 0.f, 0.f, 0.f);
      fbv = lo_b[lane];
      fb[(size_t)i * 64 + lane] = fbv;
    } else {
      const float4 r4 = xr4[(size_t)i * 64 + lane];
      const float dd = dis[i];
      float ssum = 0.f, wsum = 0.f;
      int id0 = srow[s];
      int id1 = srow[(s + 1 < e) ? s + 1 : e - 1];
      int id2 = srow[(s + 2 < e) ? s + 2 : e - 1];
      int id3 = srow[(s + 3 < e) ? s + 3 : e - 1];
      unsigned int pu0 = xlb4[(size_t)id0 * 64 + lane];
      unsigned int pu1 = xlb4[(size_t)id1 * 64 + lane];
      unsigned int pu2 = xlb4[(size_t)id2 * 64 + lane];
      unsigned int pu3 = xlb4[(size_t)id3 * 64 + lane];
      for (int p = s; p < e; p += 4) {
        const int q0 = id0, q1 = id1, q2 = id2, q3 = id3;
        const unsigned int u0 = pu0, u1 = pu1, u2 = pu2, u3 = pu3;
        const int pn = p + 4;
        if (pn < e) {
          id0 = srow[pn];
          id1 = srow[(pn + 1 < e) ? pn + 1 : e - 1];
          id2 = srow[(pn + 2 < e) ? pn + 2 : e - 1];
          id3 = srow[(pn + 3 < e) ? pn + 3 : e - 1];
          pu0 = xlb4[(size_t)id0 * 64 + lane];
          pu1 = xlb4[(size_t)id1 * 64 + lane];
          pu2 = xlb4[(size_t)id2 * 64 + lane];
          pu3 = xlb4[(size_t)id3 * 64 + lane];
        }
        const float di0 = dis[q0], di1 = dis[q1], di2 = dis[q2], di3 = dis[q3];
        const float ya = f82f(ybf_in[(size_t)q0 * 64 + lane]);
        const float yb = f82f(ybf_in[(size_t)q1 * 64 + lane]);
        const float yc = f82f(ybf_in[(size_t)q2 * 64 + lane]);
        const float yd = f82f(ybf_in[(size_t)q3 * 64 + lane]);
        float t0 = edge_logit(u0, r4, at4);
        float t1 = edge_logit(u1, r4, at4);
        float t2 = edge_logit(u2, r4, at4);
        float t3 = edge_logit(u3, r4, at4);
#pragma unroll
        for (int m = 1; m < 16; m <<= 1) {
          t0 += __shfl_xor(t0, m);
          t1 += __shfl_xor(t1, m);
          t2 += __shfl_xor(t2, m);
          t3 += __shfl_xor(t3, m);
        }
        // masked exponentials (edge 0 always valid); logits are log2-domain
        const float m1 = (p + 1 < e) ? 1.f : 0.f;
        const float m2 = (p + 2 < e) ? 1.f : 0.f;
        const float m3 = (p + 3 < e) ? 1.f : 0.f;
        const float a0 = exp2f(t0);
        const float a1 = exp2f(t1) * m1;
        const float a2 = exp2f(t2) * m2;
        const float a3 = exp2f(t3) * m3;
        ssum += (a0 + a1) + (a2 + a3);
        const float sv0 = a0 * di0, sv1 = a1 * di1, sv2 = a2 * di2, sv3 = a3 * di3;
        wsum += (sv0 + sv1) + (sv2 + sv3);
        // broadcast per-head values (group g holds head g after reduce)
        const float sa0 = __shfl(sv0, 0), sa1 = __shfl(sv0, 16);
        const float sa2 = __shfl(sv0, 32), sa3 = __shfl(sv0, 48);
        g0 = fmaf(sa0, ya, g0); g1 = fmaf(sa1, ya, g1);
        g2 = fmaf(sa2, ya, g2); g3 = fmaf(sa3, ya, g3);
        const float sb0 = __shfl(sv1, 0), sb1 = __shfl(sv1, 16);
        const float sb2 = __shfl(sv1, 32), sb3 = __shfl(sv1, 48);
        g0 = fmaf(sb0, yb, g0); g1 = fmaf(sb1, yb, g1);
        g2 = fmaf(sb2, yb, g2); g3 = fmaf(sb3, yb, g3);
        const float sc0 = __shfl(sv2, 0), sc1 = __shfl(sv2, 16);
        const float sc2 = __shfl(sv2, 32), sc3 = __shfl(sv2, 48);
        g0 = fmaf(sc0, yc, g0); g1 = fmaf(sc1, yc, g1);
        g2 = fmaf(sc2, yc, g2); g3 = fmaf(sc3, yc, g3);
        const float sd0 = __shfl(sv3, 0), sd1 = __shfl(sv3, 16);
        const float sd2 = __shfl(sv3, 32), sd3 = __shfl(sv3, 48);
        g0 = fmaf(sd0, yd, g0); g1 = fmaf(sd1, yd, g1);
        g2 = fmaf(sd2, yd, g2); g3 = fmaf(sd3, yd, g3);
        // packed edge records: lanes 0-3 each write one (contiguous 32B burst)
        const int qsel = (lane == 0) ? q0 : (lane == 1) ? q1 : (lane == 2) ? q2 : q3;
        const float e0 = (lane == 0) ? sa0 : (lane == 1) ? sb0 : (lane == 2) ? sc0 : sd0;
        const float e1 = (lane == 0) ? sa1 : (lane == 1) ? sb1 : (lane == 2) ? sc1 : sd1;
        const float e2 = (lane == 0) ? sa2 : (lane == 1) ? sb2 : (lane == 2) ? sc2 : sd2;
        const float e3 = (lane == 0) ? sa3 : (lane == 1) ? sb3 : (lane == 2) ? sc3 : sd3;
        if (lane < 4 && p + lane < e)
          erec[p + lane] = make_int2(qsel, (int)pk4f8(e0, e1, e2, e3));
      }
      const float inv = dd / (ssum > 0.f ? ssum : 1.f);
      if ((lane & 15) == 0) ((float*)&invq[i])[lane >> 4] = inv;
      const float i0h = __shfl(inv, 0), i1h = __shfl(inv, 16);
      const float i2h = __shfl(inv, 32), i3h = __shfl(inv, 48);
      g0 *= i0h; g1 *= i1h; g2 *= i2h; g3 *= i3h;
      const float wqv = wsum * inv;
      const float w0 = __shfl(wqv, 0), w1 = __shfl(wqv, 16);
      const float w2 = __shfl(wqv, 32), w3 = __shfl(wqv, 48);
      fbv = lo_b[lane];
      fbv = fmaf(w0, bb[lane], fbv);
      fbv = fmaf(w1, bb[64 + lane], fbv);
      fbv = fmaf(w2, bb[128 + lane], fbv);
      fbv = fmaf(w3, bb[192 + lane], fbv);
      fb[(size_t)i * 64 + lane] = fbv;
    }
  }
  float4 o; o.x = g0; o.y = g1; o.z = g2; o.w = g3;
  ((float4*)aggl[wave])[lane] = o;
  __syncthreads();
  float p0 = 0.f, p1 = 0.f, p2 = 0.f, p3 = 0.f;
  const float* __restrict__ wrow = Wext + (wave * 64) * 64 + lane;
#pragma unroll
  for (int q4 = 0; q4 < 16; ++q4) {
    const float4 b0 = *(const float4*)(&aggl[0][wave * 64 + q4 * 4]);
    const float4 b1 = *(const float4*)(&aggl[1][wave * 64 + q4 * 4]);
    const float4 b2 = *(const float4*)(&aggl[2][wave * 64 + q4 * 4]);
    const float4 b3 = *(const float4*)(&aggl[3][wave * 64 + q4 * 4]);
    const float w0 = wrow[(q4 * 4 + 0) * 64];
    const float w1 = wrow[(q4 * 4 + 1) * 64];
    const float w2 = wrow[(q4 * 4 + 2) * 64];
    const float w3 = wrow[(q4 * 4 + 3) * 64];
    p0 = fmaf(b0.x, w0, p0); p0 = fmaf(b0.y, w1, p0);
    p0 = fmaf(b0.z, w2, p0); p0 = fmaf(b0.w, w3, p0);
    p1 = fmaf(b1.x, w0, p1); p1 = fmaf(b1.y, w1, p1);
    p1 = fmaf(b1.z, w2, p1); p1 = fmaf(b1.w, w3, p1);
    p2 = fmaf(b2.x, w0, p2); p2 = fmaf(b2.y, w1, p2);
    p2 = fmaf(b2.z, w2, p2); p2 = fmaf(b2.w, w3, p2);
    p3 = fmaf(b3.x, w0, p3); p3 = fmaf(b3.y, w1, p3);
    p3 = fmaf(b3.z, w2, p3); p3 = fmaf(b3.w, w3, p3);
  }
  partl[wave][0][lane] = p0;
  partl[wave][1][lane] = p1;
  partl[wave][2][lane] = p2;
  partl[wave][3][lane] = p3;
  __syncthreads();
  if (i < n) {
    const size_t idx = (size_t)i * 64 + lane;
    float outv = fbv;
    outv += partl[0][wave][lane] + partl[1][wave][lane] +
            partl[2][wave][lane] + partl[3][wave][lane];
    const float y = Yin[idx], xv = X[idx];
    const float yn = fmaf(c_k, outv, fmaf(c_x, xv, c_decay * y));
    const float xn = fmaf(DT_F, yn, xv);
    float sy = yn * yn, sx = xn * xn;
#pragma unroll
    for (int m = 32; m > 0; m >>= 1) {
      sy += __shfl_xor(sy, m);
      sx += __shfl_xor(sx, m);
    }
    const float ynn = yn * rsqrtf(sy * (1.f / 64.f) + EPS_F);
    Yout[idx] = ynn;
    ybf_out[idx] = f2f8(ynn);
    X[idx] = xn * rsqrtf(sx * (1.f / 64.f) + EPS_F);
  }
}

// ---------------- K6/K7: middle layers. Masked unroll-4, packed 8B records,
// ybf-gather prefetched one block ahead (raw bytes, decode at use). VGPR<=64.
__global__ __launch_bounds__(256, 8) void layer_fused(
    const int* __restrict__ offs, const int* __restrict__ deg,
    const int2* __restrict__ erec, const float4* __restrict__ invq,
    const unsigned char* __restrict__ ybf_in, const float* __restrict__ Wext,
    const float* __restrict__ fb, const float* __restrict__ Yin,
    float* __restrict__ Yout, unsigned char* __restrict__ ybf_out,
    float* __restrict__ X, int n, float c_decay, float c_x, float c_k) {
  const int t = threadIdx.x, tr = t >> 6, lane = t & 63;
  __shared__ float aggl[4][HC];
  __shared__ float partl[4][4][64];
  const int i = blockIdx.x * 4 + tr;
  float4 o = make_float4(0.f, 0.f, 0.f, 0.f);
  if (i < n) {
    const int s = offs[i], e = s + deg[i];
    if (s < e) {
      float a0 = 0.f, a1 = 0.f, a2 = 0.f, a3 = 0.f;
      int2 c0 = erec[s];
      int2 c1 = erec[(s + 1 < e) ? s + 1 : e - 1];
      int2 c2 = erec[(s + 2 < e) ? s + 2 : e - 1];
      int2 c3 = erec[(s + 3 < e) ? s + 3 : e - 1];
      unsigned int yb0 = ybf_in[(size_t)c0.x * 64 + lane];
      unsigned int yb1 = ybf_in[(size_t)c1.x * 64 + lane];
      unsigned int yb2 = ybf_in[(size_t)c2.x * 64 + lane];
      unsigned int yb3 = ybf_in[(size_t)c3.x * 64 + lane];
      for (int p = s; p < e; p += 4) {
        const int2 d0 = c0, d1 = c1, d2 = c2, d3 = c3;
        const unsigned int z0 = yb0, z1 = yb1, z2 = yb2, z3 = yb3;
        const int pn = p + 4;
        if (pn < e) {
          c0 = erec[pn];
          c1 = erec[(pn + 1 < e) ? pn + 1 : e - 1];
          c2 = erec[(pn + 2 < e) ? pn + 2 : e - 1];
          c3 = erec[(pn + 3 < e) ? pn + 3 : e - 1];
          yb0 = ybf_in[(size_t)c0.x * 64 + lane];
          yb1 = ybf_in[(size_t)c1.x * 64 + lane];
          yb2 = ybf_in[(size_t)c2.x * 64 + lane];
          yb3 = ybf_in[(size_t)c3.x * 64 + lane];
        }
        const float m1 = (p + 1 < e) ? 1.f : 0.f;
        const float m2 = (p + 2 < e) ? 1.f : 0.f;
        const float m3 = (p + 3 < e) ? 1.f : 0.f;
        const float y0 = f82f(z0);
        const float y1 = f82f(z1) * m1;
        const float y2 = f82f(z2) * m2;
        const float y3 = f82f(z3) * m3;
        const unsigned int w0 = (unsigned int)d0.y, w1 = (unsigned int)d1.y;
        const unsigned int w2 = (unsigned int)d2.y, w3 = (unsigned int)d3.y;
        a0 = fmaf(f82f_sel0(w0), y0, a0); a1 = fmaf(f82f_sel1(w0), y0, a1);
        a2 = fmaf(f82f_sel2(w0), y0, a2); a3 = fmaf(f82f_sel3(w0), y0, a3);
        a0 = fmaf(f82f_sel0(w1), y1, a0); a1 = fmaf(f82f_sel1(w1), y1, a1);
        a2 = fmaf(f82f_sel2(w1), y1, a2); a3 = fmaf(f82f_sel3(w1), y1, a3);
        a0 = fmaf(f82f_sel0(w2), y2, a0); a1 = fmaf(f82f_sel1(w2), y2, a1);
        a2 = fmaf(f82f_sel2(w2), y2, a2); a3 = fmaf(f82f_sel3(w2), y2, a3);
        a0 = fmaf(f82f_sel0(w3), y3, a0); a1 = fmaf(f82f_sel1(w3), y3, a1);
        a2 = fmaf(f82f_sel2(w3), y3, a2); a3 = fmaf(f82f_sel3(w3), y3, a3);
      }
      const float4 iv = invq[i];
      o.x = a0 * iv.x; o.y = a1 * iv.y; o.z = a2 * iv.z; o.w = a3 * iv.w;
    }
  }
  ((float4*)aggl[tr])[lane] = o;
  __syncthreads();
  float p0 = 0.f, p1 = 0.f, p2 = 0.f, p3 = 0.f;
  const float* __restrict__ wrow = Wext + (tr * 64) * 64 + lane;
#pragma unroll
  for (int q4 = 0; q4 < 16; ++q4) {
    const float4 b0 = *(const float4*)(&aggl[0][tr * 64 + q4 * 4]);
    const float4 b1 = *(const float4*)(&aggl[1][tr * 64 + q4 * 4]);
    const float4 b2 = *(const float4*)(&aggl[2][tr * 64 + q4 * 4]);
    const float4 b3 = *(const float4*)(&aggl[3][tr * 64 + q4 * 4]);
    const float w0 = wrow[(q4 * 4 + 0) * 64];
    const float w1 = wrow[(q4 * 4 + 1) * 64];
    const float w2 = wrow[(q4 * 4 + 2) * 64];
    const float w3 = wrow[(q4 * 4 + 3) * 64];
    p0 = fmaf(b0.x, w0, p0); p0 = fmaf(b0.y, w1, p0);
    p0 = fmaf(b0.z, w2, p0); p0 = fmaf(b0.w, w3, p0);
    p1 = fmaf(b1.x, w0, p1); p1 = fmaf(b1.y, w1, p1);
    p1 = fmaf(b1.z, w2, p1); p1 = fmaf(b1.w, w3, p1);
    p2 = fmaf(b2.x, w0, p2); p2 = fmaf(b2.y, w1, p2);
    p2 = fmaf(b2.z, w2, p2); p2 = fmaf(b2.w, w3, p2);
    p3 = fmaf(b3.x, w0, p3); p3 = fmaf(b3.y, w1, p3);
    p3 = fmaf(b3.z, w2, p3); p3 = fmaf(b3.w, w3, p3);
  }
  partl[tr][0][lane] = p0;
  partl[tr][1][lane] = p1;
  partl[tr][2][lane] = p2;
  partl[tr][3][lane] = p3;
  __syncthreads();
  if (i < n) {
    const size_t idx = (size_t)i * 64 + lane;
    float outv = fb[idx];
    outv += partl[0][tr][lane] + partl[1][tr][lane] +
            partl[2][tr][lane] + partl[3][tr][lane];
    const float y = Yin[idx], xv = X[idx];
    const float yn = fmaf(c_k, outv, fmaf(c_x, xv, c_decay * y));
    const float xn = fmaf(DT_F, yn, xv);
    float sy = yn * yn, sx = xn * xn;
#pragma unroll
    for (int m = 32; m > 0; m >>= 1) {
      sy += __shfl_xor(sy, m);
      sx += __shfl_xor(sx, m);
    }
    const float ynn = yn * rsqrtf(sy * (1.f / 64.f) + EPS_F);
    Yout[idx] = ynn;
    ybf_out[idx] = f2f8(ynn);
    X[idx] = xn * rsqrtf(sx * (1.f / 64.f) + EPS_F);
  }
}

// ---------------- K8: last layer + fused decoder (same walk, no Y/ybf stores)
__global__ __launch_bounds__(256, 8) void layer_last_dec(
    const int* __restrict__ offs, const int* __restrict__ deg,
    const int2* __restrict__ erec, const float4* __restrict__ invq,
    const unsigned char* __restrict__ ybf_in, const float* __restrict__ Wext,
    const float* __restrict__ fb, const float* __restrict__ Yin,
    const float* __restrict__ X,
    const float* __restrict__ dec_w, const float* __restrict__ dec_b,
    float* __restrict__ out, int n, float c_decay, float c_x, float c_k) {
  const int t = threadIdx.x, tr = t >> 6, lane = t & 63;
  __shared__ float aggl[4][HC];
  __shared__ float partl[4][4][64];
  const int i = blockIdx.x * 4 + tr;
  float4 o = make_float4(0.f, 0.f, 0.f, 0.f);
  if (i < n) {
    const int s = offs[i], e = s + deg[i];
    if (s < e) {
      float a0 = 0.f, a1 = 0.f, a2 = 0.f, a3 = 0.f;
      int2 c0 = erec[s];
      int2 c1 = erec[(s + 1 < e) ? s + 1 : e - 1];
      int2 c2 = erec[(s + 2 < e) ? s + 2 : e - 1];
      int2 c3 = erec[(s + 3 < e) ? s + 3 : e - 1];
      unsigned int yb0 = ybf_in[(size_t)c0.x * 64 + lane];
      unsigned int yb1 = ybf_in[(size_t)c1.x * 64 + lane];
      unsigned int yb2 = ybf_in[(size_t)c2.x * 64 + lane];
      unsigned int yb3 = ybf_in[(size_t)c3.x * 64 + lane];
      for (int p = s; p < e; p += 4) {
        const int2 d0 = c0, d1 = c1, d2 = c2, d3 = c3;
        const unsigned int z0 = yb0, z1 = yb1, z2 = yb2, z3 = yb3;
        const int pn = p + 4;
        if (pn < e) {
          c0 = erec[pn];
          c1 = erec[(pn + 1 < e) ? pn + 1 : e - 1];
          c2 = erec[(pn + 2 < e) ? pn + 2 : e - 1];
          c3 = erec[(pn + 3 < e) ? pn + 3 : e - 1];
          yb0 = ybf_in[(size_t)c0.x * 64 + lane];
          yb1 = ybf_in[(size_t)c1.x * 64 + lane];
          yb2 = ybf_in[(size_t)c2.x * 64 + lane];
          yb3 = ybf_in[(size_t)c3.x * 64 + lane];
        }
        const float m1 = (p + 1 < e) ? 1.f : 0.f;
        const float m2 = (p + 2 < e) ? 1.f : 0.f;
        const float m3 = (p + 3 < e) ? 1.f : 0.f;
        const float y0 = f82f(z0);
        const float y1 = f82f(z1) * m1;
        const float y2 = f82f(z2) * m2;
        const float y3 = f82f(z3) * m3;
        const unsigned int w0 = (unsigned int)d0.y, w1 = (unsigned int)d1.y;
        const unsigned int w2 = (unsigned int)d2.y, w3 = (unsigned int)d3.y;
        a0 = fmaf(f82f_sel0(w0), y0, a0); a1 = fmaf(f82f_sel1(w0), y0, a1);
        a2 = fmaf(f82f_sel2(w0), y0, a2); a3 = fmaf(f82f_sel3(w0), y0, a3);
        a0 = fmaf(f82f_sel0(w1), y1, a0); a1 = fmaf(f82f_sel1(w1), y1, a1);
        a2 = fmaf(f82f_sel2(w1), y1, a2); a3 = fmaf(f82f_sel3(w1), y1, a3);
        a0 = fmaf(f82f_sel0(w2), y2, a0); a1 = fmaf(f82f_sel1(w2), y2, a1);
        a2 = fmaf(f82f_sel2(w2), y2, a2); a3 = fmaf(f82f_sel3(w2), y2, a3);
        a0 = fmaf(f82f_sel0(w3), y3, a0); a1 = fmaf(f82f_sel1(w3), y3, a1);
        a2 = fmaf(f82f_sel2(w3), y3, a2); a3 = fmaf(f82f_sel3(w3), y3, a3);
      }
      const float4 iv = invq[i];
      o.x = a0 * iv.x; o.y = a1 * iv.y; o.z = a2 * iv.z; o.w = a3 * iv.w;
    }
  }
  ((float4*)aggl[tr])[lane] = o;
  __syncthreads();
  float p0 = 0.f, p1 = 0.f, p2 = 0.f, p3 = 0.f;
  const float* __restrict__ wrow = Wext + (tr * 64) * 64 + lane;
#pragma unroll
  for (int q4 = 0; q4 < 16; ++q4) {
    const float4 b0 = *(const float4*)(&aggl[0][tr * 64 + q4 * 4]);
    const float4 b1 = *(const float4*)(&aggl[1][tr * 64 + q4 * 4]);
    const float4 b2 = *(const float4*)(&aggl[2][tr * 64 + q4 * 4]);
    const float4 b3 = *(const float4*)(&aggl[3][tr * 64 + q4 * 4]);
    const float w0 = wrow[(q4 * 4 + 0) * 64];
    const float w1 = wrow[(q4 * 4 + 1) * 64];
    const float w2 = wrow[(q4 * 4 + 2) * 64];
    const float w3 = wrow[(q4 * 4 + 3) * 64];
    p0 = fmaf(b0.x, w0, p0); p0 = fmaf(b0.y, w1, p0);
    p0 = fmaf(b0.z, w2, p0); p0 = fmaf(b0.w, w3, p0);
    p1 = fmaf(b1.x, w0, p1); p1 = fmaf(b1.y, w1, p1);
    p1 = fmaf(b1.z, w2, p1); p1 = fmaf(b1.w, w3, p1);
    p2 = fmaf(b2.x, w0, p2); p2 = fmaf(b2.y, w1, p2);
    p2 = fmaf(b2.z, w2, p2); p2 = fmaf(b2.w, w3, p2);
    p3 = fmaf(b3.x, w0, p3); p3 = fmaf(b3.y, w1, p3);
    p3 = fmaf(b3.z, w2, p3); p3 = fmaf(b3.w, w3, p3);
  }
  partl[tr][0][lane] = p0;
  partl[tr][1][lane] = p1;
  partl[tr][2][lane] = p2;
  partl[tr][3][lane] = p3;
  __syncthreads();
  if (i < n) {
    const size_t idx = (size_t)i * 64 + lane;
    float outv = fb[idx];
    outv += partl[0][tr][lane] + partl[1][tr][lane] +
            partl[2][tr][lane] + partl[3][tr][lane];
    const float y = Yin[idx], xv = X[idx];
    const float yn = fmaf(c_k, outv, fmaf(c_x, xv, c_decay * y));
    const float xn = fmaf(DT_F, yn, xv);
    float sx = xn * xn;
#pragma unroll
    for (int m = 32; m > 0; m >>= 1) sx += __shfl_xor(sx, m);
    const float xnn = xn * rsqrtf(sx * (1.f / 64.f) + EPS_F);
    // fused decoder: stage X row, 16-wide partial dots + xor-reduce
    aggl[tr][lane] = xnn;  // same-wave RAW: compiler inserts lgkmcnt
    const int j = lane & 15, kq = lane >> 4;
    float a = 0.f;
#pragma unroll
    for (int k2 = 0; k2 < 16; ++k2) {
      const int k = kq * 16 + k2;
      a = fmaf(aggl[tr][k], dec_w[k * NCLS + j], a);
    }
    a += __shfl_xor(a, 16);
    a += __shfl_xor(a, 32);
    if (lane < 16) out[(size_t)i * NCLS + lane] = a + dec_b[lane];
  }
}

static inline size_t alignup(size_t x) { return (x + 255) & ~(size_t)255; }

extern "C" void kernel_launch(void* const* d_in, const int* in_sizes, int n_in,
                              void* d_out, int out_size, void* d_ws, size_t ws_size,
                              hipStream_t stream) {
  const float* x     = (const float*)d_in[0];
  const float* enc_w = (const float*)d_in[1];
  const float* enc_b = (const float*)d_in[2];
  const float* dec_w = (const float*)d_in[3];
  const float* dec_b = (const float*)d_in[4];
  const float* lo_w  = (const float*)d_in[5];
  const float* lo_b  = (const float*)d_in[6];
  const float* dpl_w = (const float*)d_in[7];
  const float* dpl_b = (const float*)d_in[8];
  const float* dpr_w = (const float*)d_in[9];
  const float* dpr_b = (const float*)d_in[10];
  const float* lin_w = (const float*)d_in[11];
  const float* lin_b = (const float*)d_in[12];
  const float* att   = (const float*)d_in[13];
  const int*   ei    = (const int*)d_in[14];

  const int n = in_sizes[0] / NFEAT;
  const int E = in_sizes[14] / 2;
  const int* row = ei;
  const int* col = ei + E;

  char* p = (char*)d_ws;
  size_t off = 0;
  auto alloc = [&](size_t bytes) { void* r = p + off; off += alignup(bytes); return r; };
  float*         Y    = (float*)alloc((size_t)n * 64 * 4);
  float*         Y2   = (float*)alloc((size_t)n * 64 * 4);
  float*         X    = (float*)alloc((size_t)n * 64 * 4);
  unsigned char* ybfA = (unsigned char*)alloc((size_t)n * 64);
  unsigned char* ybfB = (unsigned char*)alloc((size_t)n * 64);
  unsigned char* xlb  = (unsigned char*)alloc((size_t)n * HC);
  float*         xr   = (float*)alloc((size_t)n * HC * 4);
  int2*          erec = (int2*)alloc((size_t)E * 8);
  int*           srow = (int*)alloc((size_t)E * 4);
  int*           deg  = (int*)alloc((size_t)n * 4);
  int*           offs = (int*)alloc((size_t)(n + 1) * 4);
  int*           cur  = (int*)alloc((size_t)n * 4);
  float*         dis  = (float*)alloc((size_t)n * 4);
  float4*        invq = (float4*)alloc((size_t)n * 16);
  float*         fb   = (float*)alloc((size_t)n * 64 * 4);
  float*         Wext = (float*)alloc((size_t)HC * 64 * 4);
  float*         bb   = (float*)alloc((size_t)HC * 4);

  const double sp = log1p(exp(1.0));  // softplus(1): omega = zeta = Ks
  const float c_decay = (float)(1.0 - 2.0 * sp * sp * 0.01);
  const float c_x     = (float)(-(sp * sp) * 0.01);
  const float c_k     = (float)(sp * 0.01);

  const int quads = (n + 3) / 4;

  enc_kernel<<<512, 256, 0, stream>>>(x, enc_w, enc_b, Y, X, ybfA, deg, n);
  proj_kernel<<<1024, 256, 0, stream>>>(Y, dpl_w, dpl_b, dpr_w, dpr_b, col,
                                        lin_w, lin_b, lo_w, xlb, xr, Wext, bb, deg,
                                        n, E);
  scan_kernel<<<1, 1024, 0, stream>>>(deg, offs, cur, dis, n);
  scatter_kernel<<<(E + 255) / 256, 256, 0, stream>>>(row, col, cur, srow, E);
  score_layer1<<<quads, 256, 0, stream>>>(offs, deg, srow, xlb, xr, att, dis, bb, lo_b,
                                          Wext, ybfA, Y, Y2, ybfB, X, erec, invq, fb,
                                          n, c_decay, c_x, c_k);
  layer_fused<<<quads, 256, 0, stream>>>(offs, deg, erec, invq, ybfB, Wext, fb,
                                         Y2, Y, ybfA, X, n, c_decay, c_x, c_k);
  layer_fused<<<quads, 256, 0, stream>>>(offs, deg, erec, invq, ybfA, Wext, fb,
                                         Y, Y2, ybfB, X, n, c_decay, c_x, c_k);
  layer_last_dec<<<quads, 256, 0, stream>>>(offs, deg, erec, invq, ybfB, Wext, fb,
                                            Y2, X, dec_w, dec_b, (float*)d_out,
                                            n, c_decay, c_x, c_k);
}

// Round 15
// 181.272 us; speedup vs baseline: 1.0995x; 1.0995x over previous
//
#include <hip/hip_runtime.h>
#include <math.h>

#define NFEAT 128
#define HC    256   // HEADS*NHID
#define NCLS  16
#define DT_F  0.01f
#define EPS_F 1e-5f
#define LOG2E 1.44269504f

// fp8 e4m3 (OCP, HW-native on gfx950) helpers
__device__ __forceinline__ unsigned char f2f8(float f) {
  int v = __builtin_amdgcn_cvt_pk_fp8_f32(f, f, 0, false);
  return (unsigned char)(v & 0xff);
}
__device__ __forceinline__ float f82f(unsigned int b) {
  return __builtin_amdgcn_cvt_f32_fp8((int)b, 0);
}
__device__ __forceinline__ float f82f_sel0(unsigned int w) { return __builtin_amdgcn_cvt_f32_fp8((int)w, 0); }
__device__ __forceinline__ float f82f_sel1(unsigned int w) { return __builtin_amdgcn_cvt_f32_fp8((int)w, 1); }
__device__ __forceinline__ float f82f_sel2(unsigned int w) { return __builtin_amdgcn_cvt_f32_fp8((int)w, 2); }
__device__ __forceinline__ float f82f_sel3(unsigned int w) { return __builtin_amdgcn_cvt_f32_fp8((int)w, 3); }

// logit in log2 domain (att pre-scaled by LOG2E)
__device__ __forceinline__ float edge_logit(unsigned int w, float4 r4, float4 at4) {
  float vx = f82f_sel0(w) + r4.x, vy = f82f_sel1(w) + r4.y;
  float vz = f82f_sel2(w) + r4.z, vw = f82f_sel3(w) + r4.w;
  vx = fmaxf(vx, 0.2f * vx); vy = fmaxf(vy, 0.2f * vy);
  vz = fmaxf(vz, 0.2f * vz); vw = fmaxf(vw, 0.2f * vw);
  float t = vx * at4.x;
  t = fmaf(vy, at4.y, t); t = fmaf(vz, at4.z, t); t = fmaf(vw, at4.w, t);
  return t;
}

// ---------------- K1: enc (Y=relu(x@enc_w+b), X=Y, ybf8=fp8(Y)) + zero deg
__global__ __launch_bounds__(256) void enc_kernel(
    const float* __restrict__ x, const float* __restrict__ w,
    const float* __restrict__ b, float* __restrict__ Y, float* __restrict__ X,
    unsigned char* __restrict__ Ybf, int* __restrict__ deg, int n) {
  __shared__ float ws[NFEAT * 64];
  const int gtid = blockIdx.x * 256 + threadIdx.x, GSZ = gridDim.x * 256;
  for (int t = gtid; t < n; t += GSZ) deg[t] = 0;
  for (int t = threadIdx.x; t < NFEAT * 64; t += blockDim.x) ws[t] = w[t];
  __syncthreads();
  const int wave = threadIdx.x >> 6, lane = threadIdx.x & 63;
  for (int i = blockIdx.x * 4 + wave; i < n; i += gridDim.x * 4) {
    const float* xr = x + (size_t)i * NFEAT;
    float acc = b[lane];
#pragma unroll 8
    for (int k = 0; k < NFEAT; ++k) acc = fmaf(xr[k], ws[k * 64 + lane], acc);
    acc = fmaxf(acc, 0.f);
    const size_t idx = (size_t)i * 64 + lane;
    Y[idx] = acc; X[idx] = acc; Ybf[idx] = f2f8(acc);
  }
}

// ---------------- K2: dual projection (xlb fp8, xr fp32) + deg count + Wext/bb
__global__ __launch_bounds__(256) void proj_kernel(
    const float* __restrict__ Y,
    const float* __restrict__ wl, const float* __restrict__ bl,
    const float* __restrict__ wr, const float* __restrict__ br,
    const int* __restrict__ col, const float* __restrict__ lin_w,
    const float* __restrict__ lin_b, const float* __restrict__ lo_w,
    unsigned char* __restrict__ xlb, float* __restrict__ xr,
    float* __restrict__ Wext, float* __restrict__ bb, int* __restrict__ deg,
    int n, int E) {
  const int half = gridDim.x >> 1;
  const bool doR = (int)blockIdx.x < half;
  const int bid = doR ? blockIdx.x : blockIdx.x - half;
  const float* __restrict__ W = doR ? wr : wl;
  const float* __restrict__ B = doR ? br : bl;
  float wreg[64];
  const int t = threadIdx.x;
#pragma unroll
  for (int k = 0; k < 64; ++k) wreg[k] = W[k * HC + t];
  const float bias = B[t];
  for (int i0 = bid * 4; i0 < n; i0 += half * 4) {
    const float* ap = Y + (size_t)i0 * 64;
    float a0 = bias, a1 = bias, a2 = bias, a3 = bias;
#pragma unroll
    for (int k = 0; k < 64; ++k) {
      const float w = wreg[k];
      a0 = fmaf(ap[k], w, a0);
      a1 = fmaf(ap[64 + k], w, a1);
      a2 = fmaf(ap[128 + k], w, a2);
      a3 = fmaf(ap[192 + k], w, a3);
    }
    if (doR) {
      if (i0 + 0 < n) xr[(size_t)(i0 + 0) * HC + t] = a0;
      if (i0 + 1 < n) xr[(size_t)(i0 + 1) * HC + t] = a1;
      if (i0 + 2 < n) xr[(size_t)(i0 + 2) * HC + t] = a2;
      if (i0 + 3 < n) xr[(size_t)(i0 + 3) * HC + t] = a3;
    } else {
      if (i0 + 0 < n) xlb[(size_t)(i0 + 0) * HC + t] = f2f8(a0);
      if (i0 + 1 < n) xlb[(size_t)(i0 + 1) * HC + t] = f2f8(a1);
      if (i0 + 2 < n) xlb[(size_t)(i0 + 2) * HC + t] = f2f8(a2);
      if (i0 + 3 < n) xlb[(size_t)(i0 + 3) * HC + t] = f2f8(a3);
    }
  }
  // appended independent work: deg count + Wext/bb
  const int gtid = blockIdx.x * 256 + t, GSZ = gridDim.x * 256;
  for (int e = gtid; e < E; e += GSZ) atomicAdd(&deg[col[e]], 1);
  for (int f = gtid; f < 260 * 64; f += GSZ) {
    const int b2 = f >> 6, j = f & 63;
    float a = 0.f;
    if (b2 < 256) {
      const int k = b2 >> 2, h = b2 & 3;
#pragma unroll 8
      for (int c = 0; c < 64; ++c)
        a = fmaf(lin_w[k * HC + h * 64 + c], lo_w[(size_t)(h * 64 + c) * 64 + j], a);
      Wext[b2 * 64 + j] = a;
    } else {
      const int h = b2 - 256;
#pragma unroll 8
      for (int c = 0; c < 64; ++c)
        a = fmaf(lin_b[h * 64 + c], lo_w[(size_t)(h * 64 + c) * 64 + j], a);
      bb[h * 64 + j] = a;
    }
  }
}

// ---------------- K3: single-block exclusive scan (1024 threads) -> offs/cur/dis
__global__ __launch_bounds__(1024) void scan_kernel(
    const int* __restrict__ deg, int* __restrict__ offsets, int* __restrict__ cursor,
    float* __restrict__ dis, int n) {
  __shared__ int part[1024];
  const int t = threadIdx.x;
  const int chunk = (n + 1023) / 1024;
  const int start = t * chunk;
  const int end = min(start + chunk, n);
  int s = 0;
  for (int i = start; i < end; ++i) s += deg[i];
  part[t] = s;
  __syncthreads();
  for (int off = 1; off < 1024; off <<= 1) {
    int v = (t >= off) ? part[t - off] : 0;
    __syncthreads();
    part[t] += v;
    __syncthreads();
  }
  int run = (t == 0) ? 0 : part[t - 1];
  for (int i = start; i < end; ++i) {
    offsets[i] = run;
    cursor[i] = run;
    const int d = deg[i];
    dis[i] = (d > 0) ? rsqrtf((float)d) : 0.f;
    run += d;
  }
}

// ---------------- K4: counting-sort src into CSR order
__global__ __launch_bounds__(256) void scatter_kernel(
    const int* __restrict__ row, const int* __restrict__ col,
    int* __restrict__ cursor, int* __restrict__ srow, int E) {
  int e = blockIdx.x * blockDim.x + threadIdx.x;
  if (e >= E) return;
  int pos = atomicAdd(&cursor[col[e]], 1);
  srow[pos] = row[e];
}

// ---------------- K5: score fused with layer-1 (round-12 structure + exp2).
// Unroll-4 edge walk with srow prefetch; sw float4 records (4x4B, one line).
__global__ __launch_bounds__(256, 8) void score_layer1(
    const int* __restrict__ offs, const int* __restrict__ deg,
    const int* __restrict__ srow,
    const unsigned char* __restrict__ xlb, const float* __restrict__ xr,
    const float* __restrict__ att, const float* __restrict__ dis,
    const float* __restrict__ bb, const float* __restrict__ lo_b,
    const float* __restrict__ Wext, const unsigned char* __restrict__ ybf_in,
    const float* __restrict__ Yin, float* __restrict__ Yout,
    unsigned char* __restrict__ ybf_out, float* __restrict__ X,
    float4* __restrict__ sw, float4* __restrict__ invq, float* __restrict__ fb,
    int n, float c_decay, float c_x, float c_k) {
  const int tid = threadIdx.x, wave = tid >> 6, lane = tid & 63;
  __shared__ float aggl[4][HC];
  __shared__ float partl[4][4][64];
  float4 at4 = ((const float4*)att)[lane];
  at4.x *= LOG2E; at4.y *= LOG2E; at4.z *= LOG2E; at4.w *= LOG2E;
  const unsigned int* xlb4 = (const unsigned int*)xlb;  // 4 fp8 per word
  const float4* xr4 = (const float4*)xr;
  const int i = blockIdx.x * 4 + wave;
  float g0 = 0.f, g1 = 0.f, g2 = 0.f, g3 = 0.f;
  float fbv = 0.f;
  if (i < n) {
    const int s = offs[i], e = s + deg[i];
    if (s >= e) {
      if (lane == 0) invq[i] = make_float4(0.f, 0.f, 0.f, 0.f);
      fbv = lo_b[lane];
      fb[(size_t)i * 64 + lane] = fbv;
    } else {
      const float4 r4 = xr4[(size_t)i * 64 + lane];
      const float dd = dis[i];
      float ssum = 0.f, wsum = 0.f;
      int p = s;
      int id0 = 0, id1 = 0, id2 = 0, id3 = 0;
      if (p + 3 < e) { id0 = srow[p]; id1 = srow[p + 1]; id2 = srow[p + 2]; id3 = srow[p + 3]; }
      while (p + 3 < e) {
        const int q0 = id0, q1 = id1, q2 = id2, q3 = id3;
        const int pn = p + 4;
        if (pn + 3 < e) { id0 = srow[pn]; id1 = srow[pn + 1]; id2 = srow[pn + 2]; id3 = srow[pn + 3]; }
        const unsigned int u0 = xlb4[(size_t)q0 * 64 + lane];
        const unsigned int u1 = xlb4[(size_t)q1 * 64 + lane];
        const unsigned int u2 = xlb4[(size_t)q2 * 64 + lane];
        const unsigned int u3 = xlb4[(size_t)q3 * 64 + lane];
        const float di0 = dis[q0], di1 = dis[q1], di2 = dis[q2], di3 = dis[q3];
        const float ya = f82f(ybf_in[(size_t)q0 * 64 + lane]);
        const float yb = f82f(ybf_in[(size_t)q1 * 64 + lane]);
        const float yc = f82f(ybf_in[(size_t)q2 * 64 + lane]);
        const float yd = f82f(ybf_in[(size_t)q3 * 64 + lane]);
        float t0 = edge_logit(u0, r4, at4);
        float t1 = edge_logit(u1, r4, at4);
        float t2 = edge_logit(u2, r4, at4);
        float t3 = edge_logit(u3, r4, at4);
#pragma unroll
        for (int m = 1; m < 16; m <<= 1) {
          t0 += __shfl_xor(t0, m);
          t1 += __shfl_xor(t1, m);
          t2 += __shfl_xor(t2, m);
          t3 += __shfl_xor(t3, m);
        }
        const float a0 = exp2f(t0), a1 = exp2f(t1), a2 = exp2f(t2), a3 = exp2f(t3);
        ssum += (a0 + a1) + (a2 + a3);
        const float sv0 = a0 * di0, sv1 = a1 * di1, sv2 = a2 * di2, sv3 = a3 * di3;
        wsum += (sv0 + sv1) + (sv2 + sv3);
        if ((lane & 15) == 0) {
          ((float*)&sw[p])[lane >> 4] = sv0;
          ((float*)&sw[p + 1])[lane >> 4] = sv1;
          ((float*)&sw[p + 2])[lane >> 4] = sv2;
          ((float*)&sw[p + 3])[lane >> 4] = sv3;
        }
        const float sa0 = __shfl(sv0, 0), sa1 = __shfl(sv0, 16);
        const float sa2 = __shfl(sv0, 32), sa3 = __shfl(sv0, 48);
        g0 = fmaf(sa0, ya, g0); g1 = fmaf(sa1, ya, g1);
        g2 = fmaf(sa2, ya, g2); g3 = fmaf(sa3, ya, g3);
        const float sb0 = __shfl(sv1, 0), sb1 = __shfl(sv1, 16);
        const float sb2 = __shfl(sv1, 32), sb3 = __shfl(sv1, 48);
        g0 = fmaf(sb0, yb, g0); g1 = fmaf(sb1, yb, g1);
        g2 = fmaf(sb2, yb, g2); g3 = fmaf(sb3, yb, g3);
        const float sc0 = __shfl(sv2, 0), sc1 = __shfl(sv2, 16);
        const float sc2 = __shfl(sv2, 32), sc3 = __shfl(sv2, 48);
        g0 = fmaf(sc0, yc, g0); g1 = fmaf(sc1, yc, g1);
        g2 = fmaf(sc2, yc, g2); g3 = fmaf(sc3, yc, g3);
        const float sd0 = __shfl(sv3, 0), sd1 = __shfl(sv3, 16);
        const float sd2 = __shfl(sv3, 32), sd3 = __shfl(sv3, 48);
        g0 = fmaf(sd0, yd, g0); g1 = fmaf(sd1, yd, g1);
        g2 = fmaf(sd2, yd, g2); g3 = fmaf(sd3, yd, g3);
        p = pn;
      }
      for (; p < e; ++p) {
        const int ra = srow[p];
        const unsigned int u0 = xlb4[(size_t)ra * 64 + lane];
        const float dia = dis[ra];
        const float ya = f82f(ybf_in[(size_t)ra * 64 + lane]);
        float t0 = edge_logit(u0, r4, at4);
#pragma unroll
        for (int m = 1; m < 16; m <<= 1) t0 += __shfl_xor(t0, m);
        const float a0 = exp2f(t0);
        ssum += a0;
        const float sv0 = a0 * dia;
        wsum += sv0;
        if ((lane & 15) == 0) ((float*)&sw[p])[lane >> 4] = sv0;
        const float sa0 = __shfl(sv0, 0), sa1 = __shfl(sv0, 16);
        const float sa2 = __shfl(sv0, 32), sa3 = __shfl(sv0, 48);
        g0 = fmaf(sa0, ya, g0); g1 = fmaf(sa1, ya, g1);
        g2 = fmaf(sa2, ya, g2); g3 = fmaf(sa3, ya, g3);
      }
      const float inv = dd / (ssum > 0.f ? ssum : 1.f);
      if ((lane & 15) == 0) ((float*)&invq[i])[lane >> 4] = inv;
      const float i0h = __shfl(inv, 0), i1h = __shfl(inv, 16);
      const float i2h = __shfl(inv, 32), i3h = __shfl(inv, 48);
      g0 *= i0h; g1 *= i1h; g2 *= i2h; g3 *= i3h;
      const float wqv = wsum * inv;
      const float w0 = __shfl(wqv, 0), w1 = __shfl(wqv, 16);
      const float w2 = __shfl(wqv, 32), w3 = __shfl(wqv, 48);
      fbv = lo_b[lane];
      fbv = fmaf(w0, bb[lane], fbv);
      fbv = fmaf(w1, bb[64 + lane], fbv);
      fbv = fmaf(w2, bb[128 + lane], fbv);
      fbv = fmaf(w3, bb[192 + lane], fbv);
      fb[(size_t)i * 64 + lane] = fbv;
    }
  }
  float4 o; o.x = g0; o.y = g1; o.z = g2; o.w = g3;
  ((float4*)aggl[wave])[lane] = o;
  __syncthreads();
  float p0 = 0.f, p1 = 0.f, p2 = 0.f, p3 = 0.f;
  const float* __restrict__ wrow = Wext + (wave * 64) * 64 + lane;
#pragma unroll
  for (int q4 = 0; q4 < 16; ++q4) {
    const float4 b0 = *(const float4*)(&aggl[0][wave * 64 + q4 * 4]);
    const float4 b1 = *(const float4*)(&aggl[1][wave * 64 + q4 * 4]);
    const float4 b2 = *(const float4*)(&aggl[2][wave * 64 + q4 * 4]);
    const float4 b3 = *(const float4*)(&aggl[3][wave * 64 + q4 * 4]);
    const float w0 = wrow[(q4 * 4 + 0) * 64];
    const float w1 = wrow[(q4 * 4 + 1) * 64];
    const float w2 = wrow[(q4 * 4 + 2) * 64];
    const float w3 = wrow[(q4 * 4 + 3) * 64];
    p0 = fmaf(b0.x, w0, p0); p0 = fmaf(b0.y, w1, p0);
    p0 = fmaf(b0.z, w2, p0); p0 = fmaf(b0.w, w3, p0);
    p1 = fmaf(b1.x, w0, p1); p1 = fmaf(b1.y, w1, p1);
    p1 = fmaf(b1.z, w2, p1); p1 = fmaf(b1.w, w3, p1);
    p2 = fmaf(b2.x, w0, p2); p2 = fmaf(b2.y, w1, p2);
    p2 = fmaf(b2.z, w2, p2); p2 = fmaf(b2.w, w3, p2);
    p3 = fmaf(b3.x, w0, p3); p3 = fmaf(b3.y, w1, p3);
    p3 = fmaf(b3.z, w2, p3); p3 = fmaf(b3.w, w3, p3);
  }
  partl[wave][0][lane] = p0;
  partl[wave][1][lane] = p1;
  partl[wave][2][lane] = p2;
  partl[wave][3][lane] = p3;
  __syncthreads();
  if (i < n) {
    const size_t idx = (size_t)i * 64 + lane;
    float outv = fbv;
    outv += partl[0][wave][lane] + partl[1][wave][lane] +
            partl[2][wave][lane] + partl[3][wave][lane];
    const float y = Yin[idx], xv = X[idx];
    const float yn = fmaf(c_k, outv, fmaf(c_x, xv, c_decay * y));
    const float xn = fmaf(DT_F, yn, xv);
    float sy = yn * yn, sx = xn * xn;
#pragma unroll
    for (int m = 32; m > 0; m >>= 1) {
      sy += __shfl_xor(sy, m);
      sx += __shfl_xor(sx, m);
    }
    const float ynn = yn * rsqrtf(sy * (1.f / 64.f) + EPS_F);
    Yout[idx] = ynn;
    ybf_out[idx] = f2f8(ynn);
    X[idx] = xn * rsqrtf(sx * (1.f / 64.f) + EPS_F);
  }
}

// ---------------- K6/K7: middle layers (round-12 structure). VGPR<=64.
__global__ __launch_bounds__(256, 8) void layer_fused(
    const int* __restrict__ offs, const int* __restrict__ deg,
    const int* __restrict__ srow,
    const float4* __restrict__ sw, const float4* __restrict__ invq,
    const unsigned char* __restrict__ ybf_in, const float* __restrict__ Wext,
    const float* __restrict__ fb, const float* __restrict__ Yin,
    float* __restrict__ Yout, unsigned char* __restrict__ ybf_out,
    float* __restrict__ X, int n, float c_decay, float c_x, float c_k) {
  const int t = threadIdx.x, tr = t >> 6, lane = t & 63;
  __shared__ float aggl[4][HC];
  __shared__ float partl[4][4][64];
  const int i = blockIdx.x * 4 + tr;
  float4 o = make_float4(0.f, 0.f, 0.f, 0.f);
  if (i < n) {
    const int s = offs[i], e = s + deg[i];
    float a0 = 0.f, a1 = 0.f, a2 = 0.f, a3 = 0.f;
    int p = s;
    int n0 = 0, n1 = 0, n2 = 0, n3 = 0;
    if (p + 3 < e) { n0 = srow[p]; n1 = srow[p + 1]; n2 = srow[p + 2]; n3 = srow[p + 3]; }
    while (p + 3 < e) {
      const int q0 = n0, q1 = n1, q2 = n2, q3 = n3;
      const int pn = p + 4;
      if (pn + 3 < e) { n0 = srow[pn]; n1 = srow[pn + 1]; n2 = srow[pn + 2]; n3 = srow[pn + 3]; }
      const float4 v0 = sw[p], v1 = sw[p + 1], v2 = sw[p + 2], v3 = sw[p + 3];
      const float y0 = f82f(ybf_in[(size_t)q0 * 64 + lane]);
      const float y1 = f82f(ybf_in[(size_t)q1 * 64 + lane]);
      const float y2 = f82f(ybf_in[(size_t)q2 * 64 + lane]);
      const float y3 = f82f(ybf_in[(size_t)q3 * 64 + lane]);
      a0 = fmaf(v0.x, y0, a0); a1 = fmaf(v0.y, y0, a1);
      a2 = fmaf(v0.z, y0, a2); a3 = fmaf(v0.w, y0, a3);
      a0 = fmaf(v1.x, y1, a0); a1 = fmaf(v1.y, y1, a1);
      a2 = fmaf(v1.z, y1, a2); a3 = fmaf(v1.w, y1, a3);
      a0 = fmaf(v2.x, y2, a0); a1 = fmaf(v2.y, y2, a1);
      a2 = fmaf(v2.z, y2, a2); a3 = fmaf(v2.w, y2, a3);
      a0 = fmaf(v3.x, y3, a0); a1 = fmaf(v3.y, y3, a1);
      a2 = fmaf(v3.z, y3, a2); a3 = fmaf(v3.w, y3, a3);
      p = pn;
    }
    for (; p < e; ++p) {
      const int r0 = srow[p];
      const float4 v0 = sw[p];
      const float y0 = f82f(ybf_in[(size_t)r0 * 64 + lane]);
      a0 = fmaf(v0.x, y0, a0); a1 = fmaf(v0.y, y0, a1);
      a2 = fmaf(v0.z, y0, a2); a3 = fmaf(v0.w, y0, a3);
    }
    const float4 iv = invq[i];
    o.x = a0 * iv.x; o.y = a1 * iv.y; o.z = a2 * iv.z; o.w = a3 * iv.w;
  }
  ((float4*)aggl[tr])[lane] = o;
  __syncthreads();
  float p0 = 0.f, p1 = 0.f, p2 = 0.f, p3 = 0.f;
  const float* __restrict__ wrow = Wext + (tr * 64) * 64 + lane;
#pragma unroll
  for (int q4 = 0; q4 < 16; ++q4) {
    const float4 b0 = *(const float4*)(&aggl[0][tr * 64 + q4 * 4]);
    const float4 b1 = *(const float4*)(&aggl[1][tr * 64 + q4 * 4]);
    const float4 b2 = *(const float4*)(&aggl[2][tr * 64 + q4 * 4]);
    const float4 b3 = *(const float4*)(&aggl[3][tr * 64 + q4 * 4]);
    const float w0 = wrow[(q4 * 4 + 0) * 64];
    const float w1 = wrow[(q4 * 4 + 1) * 64];
    const float w2 = wrow[(q4 * 4 + 2) * 64];
    const float w3 = wrow[(q4 * 4 + 3) * 64];
    p0 = fmaf(b0.x, w0, p0); p0 = fmaf(b0.y, w1, p0);
    p0 = fmaf(b0.z, w2, p0); p0 = fmaf(b0.w, w3, p0);
    p1 = fmaf(b1.x, w0, p1); p1 = fmaf(b1.y, w1, p1);
    p1 = fmaf(b1.z, w2, p1); p1 = fmaf(b1.w, w3, p1);
    p2 = fmaf(b2.x, w0, p2); p2 = fmaf(b2.y, w1, p2);
    p2 = fmaf(b2.z, w2, p2); p2 = fmaf(b2.w, w3, p2);
    p3 = fmaf(b3.x, w0, p3); p3 = fmaf(b3.y, w1, p3);
    p3 = fmaf(b3.z, w2, p3); p3 = fmaf(b3.w, w3, p3);
  }
  partl[tr][0][lane] = p0;
  partl[tr][1][lane] = p1;
  partl[tr][2][lane] = p2;
  partl[tr][3][lane] = p3;
  __syncthreads();
  if (i < n) {
    const size_t idx = (size_t)i * 64 + lane;
    float outv = fb[idx];
    outv += partl[0][tr][lane] + partl[1][tr][lane] +
            partl[2][tr][lane] + partl[3][tr][lane];
    const float y = Yin[idx], xv = X[idx];
    const float yn = fmaf(c_k, outv, fmaf(c_x, xv, c_decay * y));
    const float xn = fmaf(DT_F, yn, xv);
    float sy = yn * yn, sx = xn * xn;
#pragma unroll
    for (int m = 32; m > 0; m >>= 1) {
      sy += __shfl_xor(sy, m);
      sx += __shfl_xor(sx, m);
    }
    const float ynn = yn * rsqrtf(sy * (1.f / 64.f) + EPS_F);
    Yout[idx] = ynn;
    ybf_out[idx] = f2f8(ynn);
    X[idx] = xn * rsqrtf(sx * (1.f / 64.f) + EPS_F);
  }
}

// ---------------- K8: last layer + fused decoder (round-12 structure)
__global__ __launch_bounds__(256, 8) void layer_last_dec(
    const int* __restrict__ offs, const int* __restrict__ deg,
    const int* __restrict__ srow,
    const float4* __restrict__ sw, const float4* __restrict__ invq,
    const unsigned char* __restrict__ ybf_in, const float* __restrict__ Wext,
    const float* __restrict__ fb, const float* __restrict__ Yin,
    const float* __restrict__ X,
    const float* __restrict__ dec_w, const float* __restrict__ dec_b,
    float* __restrict__ out, int n, float c_decay, float c_x, float c_k) {
  const int t = threadIdx.x, tr = t >> 6, lane = t & 63;
  __shared__ float aggl[4][HC];
  __shared__ float partl[4][4][64];
  const int i = blockIdx.x * 4 + tr;
  float4 o = make_float4(0.f, 0.f, 0.f, 0.f);
  if (i < n) {
    const int s = offs[i], e = s + deg[i];
    float a0 = 0.f, a1 = 0.f, a2 = 0.f, a3 = 0.f;
    int p = s;
    int n0 = 0, n1 = 0, n2 = 0, n3 = 0;
    if (p + 3 < e) { n0 = srow[p]; n1 = srow[p + 1]; n2 = srow[p + 2]; n3 = srow[p + 3]; }
    while (p + 3 < e) {
      const int q0 = n0, q1 = n1, q2 = n2, q3 = n3;
      const int pn = p + 4;
      if (pn + 3 < e) { n0 = srow[pn]; n1 = srow[pn + 1]; n2 = srow[pn + 2]; n3 = srow[pn + 3]; }
      const float4 v0 = sw[p], v1 = sw[p + 1], v2 = sw[p + 2], v3 = sw[p + 3];
      const float y0 = f82f(ybf_in[(size_t)q0 * 64 + lane]);
      const float y1 = f82f(ybf_in[(size_t)q1 * 64 + lane]);
      const float y2 = f82f(ybf_in[(size_t)q2 * 64 + lane]);
      const float y3 = f82f(ybf_in[(size_t)q3 * 64 + lane]);
      a0 = fmaf(v0.x, y0, a0); a1 = fmaf(v0.y, y0, a1);
      a2 = fmaf(v0.z, y0, a2); a3 = fmaf(v0.w, y0, a3);
      a0 = fmaf(v1.x, y1, a0); a1 = fmaf(v1.y, y1, a1);
      a2 = fmaf(v1.z, y1, a2); a3 = fmaf(v1.w, y1, a3);
      a0 = fmaf(v2.x, y2, a0); a1 = fmaf(v2.y, y2, a1);
      a2 = fmaf(v2.z, y2, a2); a3 = fmaf(v2.w, y2, a3);
      a0 = fmaf(v3.x, y3, a0); a1 = fmaf(v3.y, y3, a1);
      a2 = fmaf(v3.z, y3, a2); a3 = fmaf(v3.w, y3, a3);
      p = pn;
    }
    for (; p < e; ++p) {
      const int r0 = srow[p];
      const float4 v0 = sw[p];
      const float y0 = f82f(ybf_in[(size_t)r0 * 64 + lane]);
      a0 = fmaf(v0.x, y0, a0); a1 = fmaf(v0.y, y0, a1);
      a2 = fmaf(v0.z, y0, a2); a3 = fmaf(v0.w, y0, a3);
    }
    const float4 iv = invq[i];
    o.x = a0 * iv.x; o.y = a1 * iv.y; o.z = a2 * iv.z; o.w = a3 * iv.w;
  }
  ((float4*)aggl[tr])[lane] = o;
  __syncthreads();
  float p0 = 0.f, p1 = 0.f, p2 = 0.f, p3 = 0.f;
  const float* __restrict__ wrow = Wext + (tr * 64) * 64 + lane;
#pragma unroll
  for (int q4 = 0; q4 < 16; ++q4) {
    const float4 b0 = *(const float4*)(&aggl[0][tr * 64 + q4 * 4]);
    const float4 b1 = *(const float4*)(&aggl[1][tr * 64 + q4 * 4]);
    const float4 b2 = *(const float4*)(&aggl[2][tr * 64 + q4 * 4]);
    const float4 b3 = *(const float4*)(&aggl[3][tr * 64 + q4 * 4]);
    const float w0 = wrow[(q4 * 4 + 0) * 64];
    const float w1 = wrow[(q4 * 4 + 1) * 64];
    const float w2 = wrow[(q4 * 4 + 2) * 64];
    const float w3 = wrow[(q4 * 4 + 3) * 64];
    p0 = fmaf(b0.x, w0, p0); p0 = fmaf(b0.y, w1, p0);
    p0 = fmaf(b0.z, w2, p0); p0 = fmaf(b0.w, w3, p0);
    p1 = fmaf(b1.x, w0, p1); p1 = fmaf(b1.y, w1, p1);
    p1 = fmaf(b1.z, w2, p1); p1 = fmaf(b1.w, w3, p1);
    p2 = fmaf(b2.x, w0, p2); p2 = fmaf(b2.y, w1, p2);
    p2 = fmaf(b2.z, w2, p2); p2 = fmaf(b2.w, w3, p2);
    p3 = fmaf(b3.x, w0, p3); p3 = fmaf(b3.y, w1, p3);
    p3 = fmaf(b3.z, w2, p3); p3 = fmaf(b3.w, w3, p3);
  }
  partl[tr][0][lane] = p0;
  partl[tr][1][lane] = p1;
  partl[tr][2][lane] = p2;
  partl[tr][3][lane] = p3;
  __syncthreads();
  if (i < n) {
    const size_t idx = (size_t)i * 64 + lane;
    float outv = fb[idx];
    outv += partl[0][tr][lane] + partl[1][tr][lane] +
            partl[2][tr][lane] + partl[3][tr][lane];
    const float y = Yin[idx], xv = X[idx];
    const float yn = fmaf(c_k, outv, fmaf(c_x, xv, c_decay * y));
    const float xn = fmaf(DT_F, yn, xv);
    float sx = xn * xn;
#pragma unroll
    for (int m = 32; m > 0; m >>= 1) sx += __shfl_xor(sx, m);
    const float xnn = xn * rsqrtf(sx * (1.f / 64.f) + EPS_F);
    // fused decoder: stage X row, 16-wide partial dots + xor-reduce
    aggl[tr][lane] = xnn;  // same-wave RAW: compiler inserts lgkmcnt
    const int j = lane & 15, kq = lane >> 4;
    float a = 0.f;
#pragma unroll
    for (int k2 = 0; k2 < 16; ++k2) {
      const int k = kq * 16 + k2;
      a = fmaf(aggl[tr][k], dec_w[k * NCLS + j], a);
    }
    a += __shfl_xor(a, 16);
    a += __shfl_xor(a, 32);
    if (lane < 16) out[(size_t)i * NCLS + lane] = a + dec_b[lane];
  }
}

static inline size_t alignup(size_t x) { return (x + 255) & ~(size_t)255; }

extern "C" void kernel_launch(void* const* d_in, const int* in_sizes, int n_in,
                              void* d_out, int out_size, void* d_ws, size_t ws_size,
                              hipStream_t stream) {
  const float* x     = (const float*)d_in[0];
  const float* enc_w = (const float*)d_in[1];
  const float* enc_b = (const float*)d_in[2];
  const float* dec_w = (const float*)d_in[3];
  const float* dec_b = (const float*)d_in[4];
  const float* lo_w  = (const float*)d_in[5];
  const float* lo_b  = (const float*)d_in[6];
  const float* dpl_w = (const float*)d_in[7];
  const float* dpl_b = (const float*)d_in[8];
  const float* dpr_w = (const float*)d_in[9];
  const float* dpr_b = (const float*)d_in[10];
  const float* lin_w = (const float*)d_in[11];
  const float* lin_b = (const float*)d_in[12];
  const float* att   = (const float*)d_in[13];
  const int*   ei    = (const int*)d_in[14];

  const int n = in_sizes[0] / NFEAT;
  const int E = in_sizes[14] / 2;
  const int* row = ei;
  const int* col = ei + E;

  char* p = (char*)d_ws;
  size_t off = 0;
  auto alloc = [&](size_t bytes) { void* r = p + off; off += alignup(bytes); return r; };
  float*         Y    = (float*)alloc((size_t)n * 64 * 4);
  float*         Y2   = (float*)alloc((size_t)n * 64 * 4);
  float*         X    = (float*)alloc((size_t)n * 64 * 4);
  unsigned char* ybfA = (unsigned char*)alloc((size_t)n * 64);
  unsigned char* ybfB = (unsigned char*)alloc((size_t)n * 64);
  unsigned char* xlb  = (unsigned char*)alloc((size_t)n * HC);
  float*         xr   = (float*)alloc((size_t)n * HC * 4);
  float4*        sw   = (float4*)alloc((size_t)E * 16);
  int*           srow = (int*)alloc((size_t)E * 4);
  int*           deg  = (int*)alloc((size_t)n * 4);
  int*           offs = (int*)alloc((size_t)(n + 1) * 4);
  int*           cur  = (int*)alloc((size_t)n * 4);
  float*         dis  = (float*)alloc((size_t)n * 4);
  float4*        invq = (float4*)alloc((size_t)n * 16);
  float*         fb   = (float*)alloc((size_t)n * 64 * 4);
  float*         Wext = (float*)alloc((size_t)HC * 64 * 4);
  float*         bb   = (float*)alloc((size_t)HC * 4);

  const double sp = log1p(exp(1.0));  // softplus(1): omega = zeta = Ks
  const float c_decay = (float)(1.0 - 2.0 * sp * sp * 0.01);
  const float c_x     = (float)(-(sp * sp) * 0.01);
  const float c_k     = (float)(sp * 0.01);

  const int quads = (n + 3) / 4;

  enc_kernel<<<512, 256, 0, stream>>>(x, enc_w, enc_b, Y, X, ybfA, deg, n);
  proj_kernel<<<1024, 256, 0, stream>>>(Y, dpl_w, dpl_b, dpr_w, dpr_b, col,
                                        lin_w, lin_b, lo_w, xlb, xr, Wext, bb, deg,
                                        n, E);
  scan_kernel<<<1, 1024, 0, stream>>>(deg, offs, cur, dis, n);
  scatter_kernel<<<(E + 255) / 256, 256, 0, stream>>>(row, col, cur, srow, E);
  score_layer1<<<quads, 256, 0, stream>>>(offs, deg, srow, xlb, xr, att, dis, bb, lo_b,
                                          Wext, ybfA, Y, Y2, ybfB, X, sw, invq, fb,
                                          n, c_decay, c_x, c_k);
  layer_fused<<<quads, 256, 0, stream>>>(offs, deg, srow, sw, invq, ybfB, Wext, fb,
                                         Y2, Y, ybfA, X, n, c_decay, c_x, c_k);
  layer_fused<<<quads, 256, 0, stream>>>(offs, deg, srow, sw, invq, ybfA, Wext, fb,
                                         Y, Y2, ybfB, X, n, c_decay, c_x, c_k);
  layer_last_dec<<<quads, 256, 0, stream>>>(offs, deg, srow, sw, invq, ybfB, Wext, fb,
                                            Y2, X, dec_w, dec_b, (float*)d_out,
                                            n, c_decay, c_x, c_k);
}

// Round 16
// 175.661 us; speedup vs baseline: 1.1346x; 1.0319x over previous
//
#include <hip/hip_runtime.h>
#include <math.h>

#define NFEAT 128
#define HC    256   // HEADS*NHID
#define NCLS  16
#define DT_F  0.01f
#define EPS_F 1e-5f

// fp8 e4m3 (OCP, HW-native on gfx950) helpers
__device__ __forceinline__ unsigned char f2f8(float f) {
  int v = __builtin_amdgcn_cvt_pk_fp8_f32(f, f, 0, false);
  return (unsigned char)(v & 0xff);
}
__device__ __forceinline__ float f82f(unsigned int b) {
  return __builtin_amdgcn_cvt_f32_fp8((int)b, 0);
}
__device__ __forceinline__ float f82f_sel0(unsigned int w) { return __builtin_amdgcn_cvt_f32_fp8((int)w, 0); }
__device__ __forceinline__ float f82f_sel1(unsigned int w) { return __builtin_amdgcn_cvt_f32_fp8((int)w, 1); }
__device__ __forceinline__ float f82f_sel2(unsigned int w) { return __builtin_amdgcn_cvt_f32_fp8((int)w, 2); }
__device__ __forceinline__ float f82f_sel3(unsigned int w) { return __builtin_amdgcn_cvt_f32_fp8((int)w, 3); }

__device__ __forceinline__ float edge_logit(unsigned int w, float4 r4, float4 at4) {
  float vx = f82f_sel0(w) + r4.x, vy = f82f_sel1(w) + r4.y;
  float vz = f82f_sel2(w) + r4.z, vw = f82f_sel3(w) + r4.w;
  vx = fmaxf(vx, 0.2f * vx); vy = fmaxf(vy, 0.2f * vy);
  vz = fmaxf(vz, 0.2f * vz); vw = fmaxf(vw, 0.2f * vw);
  float t = vx * at4.x;
  t = fmaf(vy, at4.y, t); t = fmaf(vz, at4.z, t); t = fmaf(vw, at4.w, t);
  return t;
}

// ---------------- K1: enc (Y=relu(x@enc_w+b), X=Y, ybf8=fp8(Y)) + zero deg
__global__ __launch_bounds__(256) void enc_kernel(
    const float* __restrict__ x, const float* __restrict__ w,
    const float* __restrict__ b, float* __restrict__ Y, float* __restrict__ X,
    unsigned char* __restrict__ Ybf, int* __restrict__ deg, int n) {
  __shared__ float ws[NFEAT * 64];
  const int gtid = blockIdx.x * 256 + threadIdx.x, GSZ = gridDim.x * 256;
  for (int t = gtid; t < n; t += GSZ) deg[t] = 0;
  for (int t = threadIdx.x; t < NFEAT * 64; t += blockDim.x) ws[t] = w[t];
  __syncthreads();
  const int wave = threadIdx.x >> 6, lane = threadIdx.x & 63;
  for (int i = blockIdx.x * 4 + wave; i < n; i += gridDim.x * 4) {
    const float* xr = x + (size_t)i * NFEAT;
    float acc = b[lane];
#pragma unroll 8
    for (int k = 0; k < NFEAT; ++k) acc = fmaf(xr[k], ws[k * 64 + lane], acc);
    acc = fmaxf(acc, 0.f);
    const size_t idx = (size_t)i * 64 + lane;
    Y[idx] = acc; X[idx] = acc; Ybf[idx] = f2f8(acc);
  }
}

// ---------------- K2: dual projection (xlb fp8, xr fp32) + deg count + Wext/bb
__global__ __launch_bounds__(256) void proj_kernel(
    const float* __restrict__ Y,
    const float* __restrict__ wl, const float* __restrict__ bl,
    const float* __restrict__ wr, const float* __restrict__ br,
    const int* __restrict__ col, const float* __restrict__ lin_w,
    const float* __restrict__ lin_b, const float* __restrict__ lo_w,
    unsigned char* __restrict__ xlb, float* __restrict__ xr,
    float* __restrict__ Wext, float* __restrict__ bb, int* __restrict__ deg,
    int n, int E) {
  const int half = gridDim.x >> 1;
  const bool doR = (int)blockIdx.x < half;
  const int bid = doR ? blockIdx.x : blockIdx.x - half;
  const float* __restrict__ W = doR ? wr : wl;
  const float* __restrict__ B = doR ? br : bl;
  float wreg[64];
  const int t = threadIdx.x;
#pragma unroll
  for (int k = 0; k < 64; ++k) wreg[k] = W[k * HC + t];
  const float bias = B[t];
  for (int i0 = bid * 4; i0 < n; i0 += half * 4) {
    const float* ap = Y + (size_t)i0 * 64;
    float a0 = bias, a1 = bias, a2 = bias, a3 = bias;
#pragma unroll
    for (int k = 0; k < 64; ++k) {
      const float w = wreg[k];
      a0 = fmaf(ap[k], w, a0);
      a1 = fmaf(ap[64 + k], w, a1);
      a2 = fmaf(ap[128 + k], w, a2);
      a3 = fmaf(ap[192 + k], w, a3);
    }
    if (doR) {
      if (i0 + 0 < n) xr[(size_t)(i0 + 0) * HC + t] = a0;
      if (i0 + 1 < n) xr[(size_t)(i0 + 1) * HC + t] = a1;
      if (i0 + 2 < n) xr[(size_t)(i0 + 2) * HC + t] = a2;
      if (i0 + 3 < n) xr[(size_t)(i0 + 3) * HC + t] = a3;
    } else {
      if (i0 + 0 < n) xlb[(size_t)(i0 + 0) * HC + t] = f2f8(a0);
      if (i0 + 1 < n) xlb[(size_t)(i0 + 1) * HC + t] = f2f8(a1);
      if (i0 + 2 < n) xlb[(size_t)(i0 + 2) * HC + t] = f2f8(a2);
      if (i0 + 3 < n) xlb[(size_t)(i0 + 3) * HC + t] = f2f8(a3);
    }
  }
  // appended independent work: deg count + Wext/bb
  const int gtid = blockIdx.x * 256 + t, GSZ = gridDim.x * 256;
  for (int e = gtid; e < E; e += GSZ) atomicAdd(&deg[col[e]], 1);
  for (int f = gtid; f < 260 * 64; f += GSZ) {
    const int b2 = f >> 6, j = f & 63;
    float a = 0.f;
    if (b2 < 256) {
      const int k = b2 >> 2, h = b2 & 3;
#pragma unroll 8
      for (int c = 0; c < 64; ++c)
        a = fmaf(lin_w[k * HC + h * 64 + c], lo_w[(size_t)(h * 64 + c) * 64 + j], a);
      Wext[b2 * 64 + j] = a;
    } else {
      const int h = b2 - 256;
#pragma unroll 8
      for (int c = 0; c < 64; ++c)
        a = fmaf(lin_b[h * 64 + c], lo_w[(size_t)(h * 64 + c) * 64 + j], a);
      bb[h * 64 + j] = a;
    }
  }
}

// ---------------- K3: single-block exclusive scan (1024 threads) -> offs/cur/dis
__global__ __launch_bounds__(1024) void scan_kernel(
    const int* __restrict__ deg, int* __restrict__ offsets, int* __restrict__ cursor,
    float* __restrict__ dis, int n) {
  __shared__ int part[1024];
  const int t = threadIdx.x;
  const int chunk = (n + 1023) / 1024;
  const int start = t * chunk;
  const int end = min(start + chunk, n);
  int s = 0;
  for (int i = start; i < end; ++i) s += deg[i];
  part[t] = s;
  __syncthreads();
  for (int off = 1; off < 1024; off <<= 1) {
    int v = (t >= off) ? part[t - off] : 0;
    __syncthreads();
    part[t] += v;
    __syncthreads();
  }
  int run = (t == 0) ? 0 : part[t - 1];
  for (int i = start; i < end; ++i) {
    offsets[i] = run;
    cursor[i] = run;
    const int d = deg[i];
    dis[i] = (d > 0) ? rsqrtf((float)d) : 0.f;
    run += d;
  }
}

// ---------------- K4: counting-sort src into CSR order
__global__ __launch_bounds__(256) void scatter_kernel(
    const int* __restrict__ row, const int* __restrict__ col,
    int* __restrict__ cursor, int* __restrict__ srow, int E) {
  int e = blockIdx.x * blockDim.x + threadIdx.x;
  if (e >= E) return;
  int pos = atomicAdd(&cursor[col[e]], 1);
  srow[pos] = row[e];
}

// ---------------- K5: score (sw/invq/fb) fused with layer-1 agg+GEMM+update.
// No persistent weight registers: GEMM streams Wext from L2 (64KB, hot).
// __launch_bounds__(256,8) pins VGPR<=64 -> 8 waves/SIMD.
__global__ __launch_bounds__(256, 8) void score_layer1(
    const int* __restrict__ offs, const int* __restrict__ deg,
    const int* __restrict__ srow,
    const unsigned char* __restrict__ xlb, const float* __restrict__ xr,
    const float* __restrict__ att, const float* __restrict__ dis,
    const float* __restrict__ bb, const float* __restrict__ lo_b,
    const float* __restrict__ Wext, const unsigned char* __restrict__ ybf_in,
    const float* __restrict__ Yin, float* __restrict__ Yout,
    unsigned char* __restrict__ ybf_out, float* __restrict__ X,
    float4* __restrict__ sw, float4* __restrict__ invq, float* __restrict__ fb,
    int n, float c_decay, float c_x, float c_k) {
  const int tid = threadIdx.x, wave = tid >> 6, lane = tid & 63;
  __shared__ float aggl[4][HC];
  __shared__ float partl[4][4][64];
  const float4 at4 = ((const float4*)att)[lane];
  const unsigned int* xlb4 = (const unsigned int*)xlb;  // 4 fp8 per word
  const float4* xr4 = (const float4*)xr;
  const int i = blockIdx.x * 4 + wave;
  float g0 = 0.f, g1 = 0.f, g2 = 0.f, g3 = 0.f;
  float fbv = 0.f;
  if (i < n) {
    const int s = offs[i], e = s + deg[i];
    if (s >= e) {
      if (lane == 0) invq[i] = make_float4(0.f, 0.f, 0.f, 0.f);
      fbv = lo_b[lane];
      fb[(size_t)i * 64 + lane] = fbv;
    } else {
      const float4 r4 = xr4[(size_t)i * 64 + lane];
      const float dd = dis[i];
      float ssum = 0.f, wsum = 0.f;
      int p = s;
      int n0 = 0, n1 = 0, n2 = 0, n3 = 0;
      if (p + 3 < e) { n0 = srow[p]; n1 = srow[p + 1]; n2 = srow[p + 2]; n3 = srow[p + 3]; }
      while (p + 3 < e) {
        const int q0 = n0, q1 = n1, q2 = n2, q3 = n3;
        const int pn = p + 4;
        if (pn + 3 < e) { n0 = srow[pn]; n1 = srow[pn + 1]; n2 = srow[pn + 2]; n3 = srow[pn + 3]; }
        const unsigned int u0 = xlb4[(size_t)q0 * 64 + lane];
        const unsigned int u1 = xlb4[(size_t)q1 * 64 + lane];
        const unsigned int u2 = xlb4[(size_t)q2 * 64 + lane];
        const unsigned int u3 = xlb4[(size_t)q3 * 64 + lane];
        const float di0 = dis[q0], di1 = dis[q1], di2 = dis[q2], di3 = dis[q3];
        const float ya = f82f(ybf_in[(size_t)q0 * 64 + lane]);
        const float yb = f82f(ybf_in[(size_t)q1 * 64 + lane]);
        const float yc = f82f(ybf_in[(size_t)q2 * 64 + lane]);
        const float yd = f82f(ybf_in[(size_t)q3 * 64 + lane]);
        float t0 = edge_logit(u0, r4, at4);
        float t1 = edge_logit(u1, r4, at4);
        float t2 = edge_logit(u2, r4, at4);
        float t3 = edge_logit(u3, r4, at4);
#pragma unroll
        for (int m = 1; m < 16; m <<= 1) {
          t0 += __shfl_xor(t0, m);
          t1 += __shfl_xor(t1, m);
          t2 += __shfl_xor(t2, m);
          t3 += __shfl_xor(t3, m);
        }
        const float a0 = __expf(t0), a1 = __expf(t1), a2 = __expf(t2), a3 = __expf(t3);
        ssum += (a0 + a1) + (a2 + a3);
        const float sv0 = a0 * di0, sv1 = a1 * di1, sv2 = a2 * di2, sv3 = a3 * di3;
        wsum += (sv0 + sv1) + (sv2 + sv3);
        if ((lane & 15) == 0) {
          ((float*)&sw[p])[lane >> 4] = sv0;
          ((float*)&sw[p + 1])[lane >> 4] = sv1;
          ((float*)&sw[p + 2])[lane >> 4] = sv2;
          ((float*)&sw[p + 3])[lane >> 4] = sv3;
        }
        const float sa0 = __shfl(sv0, 0), sa1 = __shfl(sv0, 16);
        const float sa2 = __shfl(sv0, 32), sa3 = __shfl(sv0, 48);
        g0 = fmaf(sa0, ya, g0); g1 = fmaf(sa1, ya, g1);
        g2 = fmaf(sa2, ya, g2); g3 = fmaf(sa3, ya, g3);
        const float sb0 = __shfl(sv1, 0), sb1 = __shfl(sv1, 16);
        const float sb2 = __shfl(sv1, 32), sb3 = __shfl(sv1, 48);
        g0 = fmaf(sb0, yb, g0); g1 = fmaf(sb1, yb, g1);
        g2 = fmaf(sb2, yb, g2); g3 = fmaf(sb3, yb, g3);
        const float sc0 = __shfl(sv2, 0), sc1 = __shfl(sv2, 16);
        const float sc2 = __shfl(sv2, 32), sc3 = __shfl(sv2, 48);
        g0 = fmaf(sc0, yc, g0); g1 = fmaf(sc1, yc, g1);
        g2 = fmaf(sc2, yc, g2); g3 = fmaf(sc3, yc, g3);
        const float sd0 = __shfl(sv3, 0), sd1 = __shfl(sv3, 16);
        const float sd2 = __shfl(sv3, 32), sd3 = __shfl(sv3, 48);
        g0 = fmaf(sd0, yd, g0); g1 = fmaf(sd1, yd, g1);
        g2 = fmaf(sd2, yd, g2); g3 = fmaf(sd3, yd, g3);
        p = pn;
      }
      for (; p < e; ++p) {
        const int ra = srow[p];
        const unsigned int u0 = xlb4[(size_t)ra * 64 + lane];
        const float dia = dis[ra];
        const float ya = f82f(ybf_in[(size_t)ra * 64 + lane]);
        float t0 = edge_logit(u0, r4, at4);
#pragma unroll
        for (int m = 1; m < 16; m <<= 1) t0 += __shfl_xor(t0, m);
        const float a0 = __expf(t0);
        ssum += a0;
        const float sv0 = a0 * dia;
        wsum += sv0;
        if ((lane & 15) == 0) ((float*)&sw[p])[lane >> 4] = sv0;
        const float sa0 = __shfl(sv0, 0), sa1 = __shfl(sv0, 16);
        const float sa2 = __shfl(sv0, 32), sa3 = __shfl(sv0, 48);
        g0 = fmaf(sa0, ya, g0); g1 = fmaf(sa1, ya, g1);
        g2 = fmaf(sa2, ya, g2); g3 = fmaf(sa3, ya, g3);
      }
      const float inv = dd / (ssum > 0.f ? ssum : 1.f);
      if ((lane & 15) == 0) ((float*)&invq[i])[lane >> 4] = inv;
      const float i0h = __shfl(inv, 0), i1h = __shfl(inv, 16);
      const float i2h = __shfl(inv, 32), i3h = __shfl(inv, 48);
      g0 *= i0h; g1 *= i1h; g2 *= i2h; g3 *= i3h;
      const float wqv = wsum * inv;
      const float w0 = __shfl(wqv, 0), w1 = __shfl(wqv, 16);
      const float w2 = __shfl(wqv, 32), w3 = __shfl(wqv, 48);
      fbv = lo_b[lane];
      fbv = fmaf(w0, bb[lane], fbv);
      fbv = fmaf(w1, bb[64 + lane], fbv);
      fbv = fmaf(w2, bb[128 + lane], fbv);
      fbv = fmaf(w3, bb[192 + lane], fbv);
      fb[(size_t)i * 64 + lane] = fbv;
    }
  }
  float4 o; o.x = g0; o.y = g1; o.z = g2; o.w = g3;
  ((float4*)aggl[wave])[lane] = o;
  __syncthreads();
  float p0 = 0.f, p1 = 0.f, p2 = 0.f, p3 = 0.f;
  const float* __restrict__ wrow = Wext + (wave * 64) * 64 + lane;
#pragma unroll
  for (int q4 = 0; q4 < 16; ++q4) {
    const float4 b0 = *(const float4*)(&aggl[0][wave * 64 + q4 * 4]);
    const float4 b1 = *(const float4*)(&aggl[1][wave * 64 + q4 * 4]);
    const float4 b2 = *(const float4*)(&aggl[2][wave * 64 + q4 * 4]);
    const float4 b3 = *(const float4*)(&aggl[3][wave * 64 + q4 * 4]);
    const float w0 = wrow[(q4 * 4 + 0) * 64];
    const float w1 = wrow[(q4 * 4 + 1) * 64];
    const float w2 = wrow[(q4 * 4 + 2) * 64];
    const float w3 = wrow[(q4 * 4 + 3) * 64];
    p0 = fmaf(b0.x, w0, p0); p0 = fmaf(b0.y, w1, p0);
    p0 = fmaf(b0.z, w2, p0); p0 = fmaf(b0.w, w3, p0);
    p1 = fmaf(b1.x, w0, p1); p1 = fmaf(b1.y, w1, p1);
    p1 = fmaf(b1.z, w2, p1); p1 = fmaf(b1.w, w3, p1);
    p2 = fmaf(b2.x, w0, p2); p2 = fmaf(b2.y, w1, p2);
    p2 = fmaf(b2.z, w2, p2); p2 = fmaf(b2.w, w3, p2);
    p3 = fmaf(b3.x, w0, p3); p3 = fmaf(b3.y, w1, p3);
    p3 = fmaf(b3.z, w2, p3); p3 = fmaf(b3.w, w3, p3);
  }
  partl[wave][0][lane] = p0;
  partl[wave][1][lane] = p1;
  partl[wave][2][lane] = p2;
  partl[wave][3][lane] = p3;
  __syncthreads();
  if (i < n) {
    const size_t idx = (size_t)i * 64 + lane;
    float outv = fbv;
    outv += partl[0][wave][lane] + partl[1][wave][lane] +
            partl[2][wave][lane] + partl[3][wave][lane];
    const float y = Yin[idx], xv = X[idx];
    const float yn = fmaf(c_k, outv, fmaf(c_x, xv, c_decay * y));
    const float xn = fmaf(DT_F, yn, xv);
    float sy = yn * yn, sx = xn * xn;
#pragma unroll
    for (int m = 32; m > 0; m >>= 1) {
      sy += __shfl_xor(sy, m);
      sx += __shfl_xor(sx, m);
    }
    const float ynn = yn * rsqrtf(sy * (1.f / 64.f) + EPS_F);
    Yout[idx] = ynn;
    ybf_out[idx] = f2f8(ynn);
    X[idx] = xn * rsqrtf(sx * (1.f / 64.f) + EPS_F);
  }
}

// ---------------- K6/K7: middle layers, no weight registers, VGPR<=64.
__global__ __launch_bounds__(256, 8) void layer_fused(
    const int* __restrict__ offs, const int* __restrict__ deg,
    const int* __restrict__ srow,
    const float4* __restrict__ sw, const float4* __restrict__ invq,
    const unsigned char* __restrict__ ybf_in, const float* __restrict__ Wext,
    const float* __restrict__ fb, const float* __restrict__ Yin,
    float* __restrict__ Yout, unsigned char* __restrict__ ybf_out,
    float* __restrict__ X, int n, float c_decay, float c_x, float c_k) {
  const int t = threadIdx.x, tr = t >> 6, lane = t & 63;
  __shared__ float aggl[4][HC];
  __shared__ float partl[4][4][64];
  const int i = blockIdx.x * 4 + tr;
  float4 o = make_float4(0.f, 0.f, 0.f, 0.f);
  if (i < n) {
    const int s = offs[i], e = s + deg[i];
    float a0 = 0.f, a1 = 0.f, a2 = 0.f, a3 = 0.f;
    int p = s;
    int n0 = 0, n1 = 0, n2 = 0, n3 = 0;
    if (p + 3 < e) { n0 = srow[p]; n1 = srow[p + 1]; n2 = srow[p + 2]; n3 = srow[p + 3]; }
    while (p + 3 < e) {
      const int q0 = n0, q1 = n1, q2 = n2, q3 = n3;
      const int pn = p + 4;
      if (pn + 3 < e) { n0 = srow[pn]; n1 = srow[pn + 1]; n2 = srow[pn + 2]; n3 = srow[pn + 3]; }
      const float4 v0 = sw[p], v1 = sw[p + 1], v2 = sw[p + 2], v3 = sw[p + 3];
      const float y0 = f82f(ybf_in[(size_t)q0 * 64 + lane]);
      const float y1 = f82f(ybf_in[(size_t)q1 * 64 + lane]);
      const float y2 = f82f(ybf_in[(size_t)q2 * 64 + lane]);
      const float y3 = f82f(ybf_in[(size_t)q3 * 64 + lane]);
      a0 = fmaf(v0.x, y0, a0); a1 = fmaf(v0.y, y0, a1);
      a2 = fmaf(v0.z, y0, a2); a3 = fmaf(v0.w, y0, a3);
      a0 = fmaf(v1.x, y1, a0); a1 = fmaf(v1.y, y1, a1);
      a2 = fmaf(v1.z, y1, a2); a3 = fmaf(v1.w, y1, a3);
      a0 = fmaf(v2.x, y2, a0); a1 = fmaf(v2.y, y2, a1);
      a2 = fmaf(v2.z, y2, a2); a3 = fmaf(v2.w, y2, a3);
      a0 = fmaf(v3.x, y3, a0); a1 = fmaf(v3.y, y3, a1);
      a2 = fmaf(v3.z, y3, a2); a3 = fmaf(v3.w, y3, a3);
      p = pn;
    }
    for (; p < e; ++p) {
      const int r0 = srow[p];
      const float4 v0 = sw[p];
      const float y0 = f82f(ybf_in[(size_t)r0 * 64 + lane]);
      a0 = fmaf(v0.x, y0, a0); a1 = fmaf(v0.y, y0, a1);
      a2 = fmaf(v0.z, y0, a2); a3 = fmaf(v0.w, y0, a3);
    }
    const float4 iv = invq[i];
    o.x = a0 * iv.x; o.y = a1 * iv.y; o.z = a2 * iv.z; o.w = a3 * iv.w;
  }
  ((float4*)aggl[tr])[lane] = o;
  __syncthreads();
  float p0 = 0.f, p1 = 0.f, p2 = 0.f, p3 = 0.f;
  const float* __restrict__ wrow = Wext + (tr * 64) * 64 + lane;
#pragma unroll
  for (int q4 = 0; q4 < 16; ++q4) {
    const float4 b0 = *(const float4*)(&aggl[0][tr * 64 + q4 * 4]);
    const float4 b1 = *(const float4*)(&aggl[1][tr * 64 + q4 * 4]);
    const float4 b2 = *(const float4*)(&aggl[2][tr * 64 + q4 * 4]);
    const float4 b3 = *(const float4*)(&aggl[3][tr * 64 + q4 * 4]);
    const float w0 = wrow[(q4 * 4 + 0) * 64];
    const float w1 = wrow[(q4 * 4 + 1) * 64];
    const float w2 = wrow[(q4 * 4 + 2) * 64];
    const float w3 = wrow[(q4 * 4 + 3) * 64];
    p0 = fmaf(b0.x, w0, p0); p0 = fmaf(b0.y, w1, p0);
    p0 = fmaf(b0.z, w2, p0); p0 = fmaf(b0.w, w3, p0);
    p1 = fmaf(b1.x, w0, p1); p1 = fmaf(b1.y, w1, p1);
    p1 = fmaf(b1.z, w2, p1); p1 = fmaf(b1.w, w3, p1);
    p2 = fmaf(b2.x, w0, p2); p2 = fmaf(b2.y, w1, p2);
    p2 = fmaf(b2.z, w2, p2); p2 = fmaf(b2.w, w3, p2);
    p3 = fmaf(b3.x, w0, p3); p3 = fmaf(b3.y, w1, p3);
    p3 = fmaf(b3.z, w2, p3); p3 = fmaf(b3.w, w3, p3);
  }
  partl[tr][0][lane] = p0;
  partl[tr][1][lane] = p1;
  partl[tr][2][lane] = p2;
  partl[tr][3][lane] = p3;
  __syncthreads();
  if (i < n) {
    const size_t idx = (size_t)i * 64 + lane;
    float outv = fb[idx];
    outv += partl[0][tr][lane] + partl[1][tr][lane] +
            partl[2][tr][lane] + partl[3][tr][lane];
    const float y = Yin[idx], xv = X[idx];
    const float yn = fmaf(c_k, outv, fmaf(c_x, xv, c_decay * y));
    const float xn = fmaf(DT_F, yn, xv);
    float sy = yn * yn, sx = xn * xn;
#pragma unroll
    for (int m = 32; m > 0; m >>= 1) {
      sy += __shfl_xor(sy, m);
      sx += __shfl_xor(sx, m);
    }
    const float ynn = yn * rsqrtf(sy * (1.f / 64.f) + EPS_F);
    Yout[idx] = ynn;
    ybf_out[idx] = f2f8(ynn);
    X[idx] = xn * rsqrtf(sx * (1.f / 64.f) + EPS_F);
  }
}

// ---------------- K8: last layer + fused decoder, no weight registers.
__global__ __launch_bounds__(256, 8) void layer_last_dec(
    const int* __restrict__ offs, const int* __restrict__ deg,
    const int* __restrict__ srow,
    const float4* __restrict__ sw, const float4* __restrict__ invq,
    const unsigned char* __restrict__ ybf_in, const float* __restrict__ Wext,
    const float* __restrict__ fb, const float* __restrict__ Yin,
    const float* __restrict__ X,
    const float* __restrict__ dec_w, const float* __restrict__ dec_b,
    float* __restrict__ out, int n, float c_decay, float c_x, float c_k) {
  const int t = threadIdx.x, tr = t >> 6, lane = t & 63;
  __shared__ float aggl[4][HC];
  __shared__ float partl[4][4][64];
  const int i = blockIdx.x * 4 + tr;
  float4 o = make_float4(0.f, 0.f, 0.f, 0.f);
  if (i < n) {
    const int s = offs[i], e = s + deg[i];
    float a0 = 0.f, a1 = 0.f, a2 = 0.f, a3 = 0.f;
    int p = s;
    int n0 = 0, n1 = 0, n2 = 0, n3 = 0;
    if (p + 3 < e) { n0 = srow[p]; n1 = srow[p + 1]; n2 = srow[p + 2]; n3 = srow[p + 3]; }
    while (p + 3 < e) {
      const int q0 = n0, q1 = n1, q2 = n2, q3 = n3;
      const int pn = p + 4;
      if (pn + 3 < e) { n0 = srow[pn]; n1 = srow[pn + 1]; n2 = srow[pn + 2]; n3 = srow[pn + 3]; }
      const float4 v0 = sw[p], v1 = sw[p + 1], v2 = sw[p + 2], v3 = sw[p + 3];
      const float y0 = f82f(ybf_in[(size_t)q0 * 64 + lane]);
      const float y1 = f82f(ybf_in[(size_t)q1 * 64 + lane]);
      const float y2 = f82f(ybf_in[(size_t)q2 * 64 + lane]);
      const float y3 = f82f(ybf_in[(size_t)q3 * 64 + lane]);
      a0 = fmaf(v0.x, y0, a0); a1 = fmaf(v0.y, y0, a1);
      a2 = fmaf(v0.z, y0, a2); a3 = fmaf(v0.w, y0, a3);
      a0 = fmaf(v1.x, y1, a0); a1 = fmaf(v1.y, y1, a1);
      a2 = fmaf(v1.z, y1, a2); a3 = fmaf(v1.w, y1, a3);
      a0 = fmaf(v2.x, y2, a0); a1 = fmaf(v2.y, y2, a1);
      a2 = fmaf(v2.z, y2, a2); a3 = fmaf(v2.w, y2, a3);
      a0 = fmaf(v3.x, y3, a0); a1 = fmaf(v3.y, y3, a1);
      a2 = fmaf(v3.z, y3, a2); a3 = fmaf(v3.w, y3, a3);
      p = pn;
    }
    for (; p < e; ++p) {
      const int r0 = srow[p];
      const float4 v0 = sw[p];
      const float y0 = f82f(ybf_in[(size_t)r0 * 64 + lane]);
      a0 = fmaf(v0.x, y0, a0); a1 = fmaf(v0.y, y0, a1);
      a2 = fmaf(v0.z, y0, a2); a3 = fmaf(v0.w, y0, a3);
    }
    const float4 iv = invq[i];
    o.x = a0 * iv.x; o.y = a1 * iv.y; o.z = a2 * iv.z; o.w = a3 * iv.w;
  }
  ((float4*)aggl[tr])[lane] = o;
  __syncthreads();
  float p0 = 0.f, p1 = 0.f, p2 = 0.f, p3 = 0.f;
  const float* __restrict__ wrow = Wext + (tr * 64) * 64 + lane;
#pragma unroll
  for (int q4 = 0; q4 < 16; ++q4) {
    const float4 b0 = *(const float4*)(&aggl[0][tr * 64 + q4 * 4]);
    const float4 b1 = *(const float4*)(&aggl[1][tr * 64 + q4 * 4]);
    const float4 b2 = *(const float4*)(&aggl[2][tr * 64 + q4 * 4]);
    const float4 b3 = *(const float4*)(&aggl[3][tr * 64 + q4 * 4]);
    const float w0 = wrow[(q4 * 4 + 0) * 64];
    const float w1 = wrow[(q4 * 4 + 1) * 64];
    const float w2 = wrow[(q4 * 4 + 2) * 64];
    const float w3 = wrow[(q4 * 4 + 3) * 64];
    p0 = fmaf(b0.x, w0, p0); p0 = fmaf(b0.y, w1, p0);
    p0 = fmaf(b0.z, w2, p0); p0 = fmaf(b0.w, w3, p0);
    p1 = fmaf(b1.x, w0, p1); p1 = fmaf(b1.y, w1, p1);
    p1 = fmaf(b1.z, w2, p1); p1 = fmaf(b1.w, w3, p1);
    p2 = fmaf(b2.x, w0, p2); p2 = fmaf(b2.y, w1, p2);
    p2 = fmaf(b2.z, w2, p2); p2 = fmaf(b2.w, w3, p2);
    p3 = fmaf(b3.x, w0, p3); p3 = fmaf(b3.y, w1, p3);
    p3 = fmaf(b3.z, w2, p3); p3 = fmaf(b3.w, w3, p3);
  }
  partl[tr][0][lane] = p0;
  partl[tr][1][lane] = p1;
  partl[tr][2][lane] = p2;
  partl[tr][3][lane] = p3;
  __syncthreads();
  if (i < n) {
    const size_t idx = (size_t)i * 64 + lane;
    float outv = fb[idx];
    outv += partl[0][tr][lane] + partl[1][tr][lane] +
            partl[2][tr][lane] + partl[3][tr][lane];
    const float y = Yin[idx], xv = X[idx];
    const float yn = fmaf(c_k, outv, fmaf(c_x, xv, c_decay * y));
    const float xn = fmaf(DT_F, yn, xv);
    float sx = xn * xn;
#pragma unroll
    for (int m = 32; m > 0; m >>= 1) sx += __shfl_xor(sx, m);
    const float xnn = xn * rsqrtf(sx * (1.f / 64.f) + EPS_F);
    // fused decoder: stage X row, 16-wide partial dots + xor-reduce
    aggl[tr][lane] = xnn;  // same-wave RAW: compiler inserts lgkmcnt
    const int j = lane & 15, kq = lane >> 4;
    float a = 0.f;
#pragma unroll
    for (int k2 = 0; k2 < 16; ++k2) {
      const int k = kq * 16 + k2;
      a = fmaf(aggl[tr][k], dec_w[k * NCLS + j], a);
    }
    a += __shfl_xor(a, 16);
    a += __shfl_xor(a, 32);
    if (lane < 16) out[(size_t)i * NCLS + lane] = a + dec_b[lane];
  }
}

static inline size_t alignup(size_t x) { return (x + 255) & ~(size_t)255; }

extern "C" void kernel_launch(void* const* d_in, const int* in_sizes, int n_in,
                              void* d_out, int out_size, void* d_ws, size_t ws_size,
                              hipStream_t stream) {
  const float* x     = (const float*)d_in[0];
  const float* enc_w = (const float*)d_in[1];
  const float* enc_b = (const float*)d_in[2];
  const float* dec_w = (const float*)d_in[3];
  const float* dec_b = (const float*)d_in[4];
  const float* lo_w  = (const float*)d_in[5];
  const float* lo_b  = (const float*)d_in[6];
  const float* dpl_w = (const float*)d_in[7];
  const float* dpl_b = (const float*)d_in[8];
  const float* dpr_w = (const float*)d_in[9];
  const float* dpr_b = (const float*)d_in[10];
  const float* lin_w = (const float*)d_in[11];
  const float* lin_b = (const float*)d_in[12];
  const float* att   = (const float*)d_in[13];
  const int*   ei    = (const int*)d_in[14];

  const int n = in_sizes[0] / NFEAT;
  const int E = in_sizes[14] / 2;
  const int* row = ei;
  const int* col = ei + E;

  char* p = (char*)d_ws;
  size_t off = 0;
  auto alloc = [&](size_t bytes) { void* r = p + off; off += alignup(bytes); return r; };
  float*         Y    = (float*)alloc((size_t)n * 64 * 4);
  float*         Y2   = (float*)alloc((size_t)n * 64 * 4);
  float*         X    = (float*)alloc((size_t)n * 64 * 4);
  unsigned char* ybfA = (unsigned char*)alloc((size_t)n * 64);
  unsigned char* ybfB = (unsigned char*)alloc((size_t)n * 64);
  unsigned char* xlb  = (unsigned char*)alloc((size_t)n * HC);
  float*         xr   = (float*)alloc((size_t)n * HC * 4);
  float4*        sw   = (float4*)alloc((size_t)E * 16);
  int*           srow = (int*)alloc((size_t)E * 4);
  int*           deg  = (int*)alloc((size_t)n * 4);
  int*           offs = (int*)alloc((size_t)(n + 1) * 4);
  int*           cur  = (int*)alloc((size_t)n * 4);
  float*         dis  = (float*)alloc((size_t)n * 4);
  float4*        invq = (float4*)alloc((size_t)n * 16);
  float*         fb   = (float*)alloc((size_t)n * 64 * 4);
  float*         Wext = (float*)alloc((size_t)HC * 64 * 4);
  float*         bb   = (float*)alloc((size_t)HC * 4);

  const double sp = log1p(exp(1.0));  // softplus(1): omega = zeta = Ks
  const float c_decay = (float)(1.0 - 2.0 * sp * sp * 0.01);
  const float c_x     = (float)(-(sp * sp) * 0.01);
  const float c_k     = (float)(sp * 0.01);

  const int quads = (n + 3) / 4;

  enc_kernel<<<512, 256, 0, stream>>>(x, enc_w, enc_b, Y, X, ybfA, deg, n);
  proj_kernel<<<1024, 256, 0, stream>>>(Y, dpl_w, dpl_b, dpr_w, dpr_b, col,
                                        lin_w, lin_b, lo_w, xlb, xr, Wext, bb, deg,
                                        n, E);
  scan_kernel<<<1, 1024, 0, stream>>>(deg, offs, cur, dis, n);
  scatter_kernel<<<(E + 255) / 256, 256, 0, stream>>>(row, col, cur, srow, E);
  score_layer1<<<quads, 256, 0, stream>>>(offs, deg, srow, xlb, xr, att, dis, bb, lo_b,
                                          Wext, ybfA, Y, Y2, ybfB, X, sw, invq, fb,
                                          n, c_decay, c_x, c_k);
  layer_fused<<<quads, 256, 0, stream>>>(offs, deg, srow, sw, invq, ybfB, Wext, fb,
                                         Y2, Y, ybfA, X, n, c_decay, c_x, c_k);
  layer_fused<<<quads, 256, 0, stream>>>(offs, deg, srow, sw, invq, ybfA, Wext, fb,
                                         Y, Y2, ybfB, X, n, c_decay, c_x, c_k);
  layer_last_dec<<<quads, 256, 0, stream>>>(offs, deg, srow, sw, invq, ybfB, Wext, fb,
                                            Y2, X, dec_w, dec_b, (float*)d_out,
                                            n, c_decay, c_x, c_k);
}